// Round 1
// baseline (502.477 us; speedup 1.0000x reference)
//
#include <hip/hip_runtime.h>

#define CC 16      // channels
#define KK 3       // kernel taps
#define LL 16      // layers
#define TT 32768   // time
#define BB 8       // batch
#define TLOG 15    // log2(T)

// ---------------- input conv (1x1) + skip_acc init ----------------
__global__ __launch_bounds__(256) void wn_input_conv(
    const float* __restrict__ x, const float* __restrict__ in_w,
    const float* __restrict__ in_b, float* __restrict__ out,
    float* __restrict__ skip_acc) {
  int idx = blockIdx.x * 256 + threadIdx.x;   // b*T + t
  float xv = x[idx];
  int b = idx >> TLOG;
  int t = idx & (TT - 1);
#pragma unroll
  for (int c = 0; c < CC; ++c) {
    out[(((b * CC) + c) << TLOG) + t] = fmaf(in_w[c], xv, in_b[c]);
  }
  skip_acc[idx] = 0.f;
}

// ---------------- one WaveNet layer, fully fused ----------------
template <bool LAST>
__global__ __launch_bounds__(256) void wn_layer(
    const float* __restrict__ src, float* __restrict__ dst,
    const float* __restrict__ hid_w, const float* __restrict__ hid_b,
    const float* __restrict__ res_w, const float* __restrict__ res_b,
    const float* __restrict__ mix_w, const float* __restrict__ mix_b,
    float* __restrict__ skip_acc, float* __restrict__ out,
    int layer, int dil) {
  int idx = blockIdx.x * 256 + threadIdx.x;   // b*T + t
  int b = idx >> TLOG;
  int t = idx & (TT - 1);

  // ---- load 16 channels x 3 taps of input (coalesced across t) ----
  float xv[CC * KK];
#pragma unroll
  for (int ci = 0; ci < CC; ++ci) {
#pragma unroll
    for (int k = 0; k < KK; ++k) {
      int tt = t - (2 - k) * dil;             // causal left pad
      xv[ci * KK + k] = (tt >= 0) ? src[(((b * CC) + ci) << TLOG) + tt] : 0.f;
    }
  }

  // ---- dilated conv: h[32] = hid_b + W @ xv (weights uniform -> s_load) ----
  const float* W  = hid_w + (size_t)layer * (2 * CC * CC * KK);
  const float* hb = hid_b + layer * (2 * CC);
  float h[2 * CC];
#pragma unroll
  for (int co = 0; co < 2 * CC; ++co) {
    float acc = hb[co];
#pragma unroll
    for (int j = 0; j < CC * KK; ++j) {
      acc = fmaf(W[co * (CC * KK) + j], xv[j], acc);
    }
    h[co] = acc;
  }

  // ---- gated = tanh(h[:16]) * sigmoid(h[16:]) ----
  float gated[CC];
#pragma unroll
  for (int c = 0; c < CC; ++c) {
    float a = fminf(fmaxf(h[c], -15.f), 15.f);
    float ea = __expf(2.f * a);
    float th = (ea - 1.f) / (ea + 1.f);
    float bq = fminf(fmaxf(h[c + CC], -30.f), 30.f);
    float sg = 1.f / (1.f + __expf(-bq));
    gated[c] = th * sg;
  }

  // ---- skip contribution (mix conv folded in) ----
  const float* mw = mix_w + layer * CC;
  float s = 0.f;
#pragma unroll
  for (int c = 0; c < CC; ++c) s = fmaf(mw[c], gated[c], s);

  if (LAST) {
    // final layer: res conv output is unused; emit final mix directly
    out[idx] = skip_acc[idx] + s + mix_b[0];
  } else {
    skip_acc[idx] += s;
    // ---- 1x1 res conv + residual (center tap xv[c][2] == src[t]) ----
    const float* RW = res_w + layer * (CC * CC);
    const float* rb = res_b + layer * CC;
#pragma unroll
    for (int c = 0; c < CC; ++c) {
      float acc = rb[c];
#pragma unroll
      for (int c2 = 0; c2 < CC; ++c2) {
        acc = fmaf(RW[c * CC + c2], gated[c2], acc);
      }
      dst[(((b * CC) + c) << TLOG) + t] = acc + xv[c * KK + 2];
    }
  }
}

extern "C" void kernel_launch(void* const* d_in, const int* in_sizes, int n_in,
                              void* d_out, int out_size, void* d_ws, size_t ws_size,
                              hipStream_t stream) {
  const float* x     = (const float*)d_in[0];
  const float* in_w  = (const float*)d_in[1];
  const float* in_b  = (const float*)d_in[2];
  const float* hid_w = (const float*)d_in[3];
  const float* hid_b = (const float*)d_in[4];
  const float* res_w = (const float*)d_in[5];
  const float* res_b = (const float*)d_in[6];
  const float* mix_w = (const float*)d_in[7];
  const float* mix_b = (const float*)d_in[8];
  float* outp = (float*)d_out;

  float* ws = (float*)d_ws;
  const size_t STATE = (size_t)BB * CC * TT;       // 4,194,304 floats
  float* s0   = ws;
  float* s1   = ws + STATE;
  float* skip = ws + 2 * STATE;                    // B*T floats

  dim3 block(256);
  dim3 grid((BB * TT) / 256);                      // 1024 blocks

  wn_input_conv<<<grid, block, 0, stream>>>(x, in_w, in_b, s0, skip);

  const float* src = s0;
  float* dst = s1;
  for (int i = 0; i < LL; ++i) {
    int d = 1 << (i & 7);
    if (i == LL - 1) {
      wn_layer<true><<<grid, block, 0, stream>>>(
          src, dst, hid_w, hid_b, res_w, res_b, mix_w, mix_b, skip, outp, i, d);
    } else {
      wn_layer<false><<<grid, block, 0, stream>>>(
          src, dst, hid_w, hid_b, res_w, res_b, mix_w, mix_b, skip, outp, i, d);
    }
    const float* tmp = dst;
    dst = (float*)src;
    src = tmp;
  }
}

// Round 2
// 399.065 us; speedup vs baseline: 1.2591x; 1.2591x over previous
//
#include <hip/hip_runtime.h>

#define CC 16      // channels
#define KK 3       // kernel taps
#define LL 16      // layers
#define TT 32768   // time
#define BB 8       // batch
#define PADL 256   // left zero-pad (>= 2*max_dilation)
#define ROWS (TT + PADL)                 // 33024 floats per (b,c) row
#define STATE ((size_t)BB * CC * ROWS)   // floats per state buffer

__device__ __forceinline__ float2 ld2(const float* p) {
  return *reinterpret_cast<const float2*>(p);
}

__device__ __forceinline__ float gate_fn(float a, float b) {
  // tanh(a) * sigmoid(b), fast approx (abs tol 1.14e-2; rcp/exp err ~1e-6)
  float aa = fminf(fmaxf(a, -15.f), 15.f);
  float ea = __expf(2.f * aa);
  float th = 1.f - 2.f * __builtin_amdgcn_rcpf(ea + 1.f);
  float bb = fminf(fmaxf(b, -30.f), 30.f);
  float sg = __builtin_amdgcn_rcpf(1.f + __expf(-bb));
  return th * sg;
}

// ------------- one-time weight transpose -------------
// hid_w [L,2C,C,K] -> Wt [L][ci][k][co]   (co contiguous)
// res_w [L,C,C]    -> Rt [L][c2][c]       (c contiguous)
__global__ __launch_bounds__(256) void wn_prep(
    const float* __restrict__ hid_w, const float* __restrict__ res_w,
    float* __restrict__ Wt, float* __restrict__ Rt) {
  int tid = blockIdx.x * 256 + threadIdx.x;
  if (tid < LL * 2 * CC * CC * KK) {
    int k = tid % KK;
    int r = tid / KK;
    int ci = r % CC; r /= CC;
    int co = r % (2 * CC);
    int l = r / (2 * CC);
    Wt[((l * CC + ci) * KK + k) * (2 * CC) + co] = hid_w[tid];
  }
  int rid = tid - LL * 2 * CC * CC * KK;
  if (rid >= 0 && rid < LL * CC * CC) {
    int c2 = rid % CC;
    int r = rid / CC;
    int c = r % CC;
    int l = r / CC;
    Rt[(l * CC + c2) * CC + c] = res_w[rid];
  }
}

// ------------- zero the left pads of both state buffers -------------
__global__ __launch_bounds__(256) void wn_zero_pads(float* __restrict__ s0,
                                                    float* __restrict__ s1) {
  int tid = blockIdx.x * 256 + threadIdx.x;   // 2 * BB*CC*PADL = 65536
  float* s = (tid >> 15) ? s1 : s0;
  int r = tid & 32767;                        // BB*CC*PADL - 1
  int row = r >> 8;                           // PADL = 256
  int off = r & 255;
  s[(size_t)row * ROWS + off] = 0.f;
}

// ------------- input 1x1 conv + skip init -------------
__global__ __launch_bounds__(256) void wn_input(
    const float* __restrict__ x, const float* __restrict__ in_w,
    const float* __restrict__ in_b, float* __restrict__ out,
    float* __restrict__ skip) {
  int tid = blockIdx.x * 256 + threadIdx.x;   // BB*TT/4 = 65536
  int b = tid >> 13;
  int t4 = (tid & 8191) << 2;
  float4 xv = *reinterpret_cast<const float4*>(x + ((size_t)b << 15) + t4);
#pragma unroll
  for (int c = 0; c < CC; ++c) {
    float w = in_w[c], bi = in_b[c];
    float4 o{fmaf(w, xv.x, bi), fmaf(w, xv.y, bi),
             fmaf(w, xv.z, bi), fmaf(w, xv.w, bi)};
    *reinterpret_cast<float4*>(out + (size_t)(b * CC + c) * ROWS + PADL + t4) = o;
  }
  *reinterpret_cast<float4*>(skip + ((size_t)b << 15) + t4) = float4{0, 0, 0, 0};
}

// ------------- one fused WaveNet layer, 2 time-steps per thread -------------
template <int D, bool LAST>
__global__ __launch_bounds__(256) void wn_layer(
    const float* __restrict__ src, float* __restrict__ dst,
    const float* __restrict__ Wt, const float* __restrict__ hid_b,
    const float* __restrict__ Rt, const float* __restrict__ res_b,
    const float* __restrict__ mix_w, const float* __restrict__ mix_b,
    float* __restrict__ skip, float* __restrict__ out, int layer) {
  int tid = blockIdx.x * 256 + threadIdx.x;   // BB*TT/2 = 131072 threads
  int b = tid >> 14;
  int t2 = (tid & 16383) << 1;                // this thread: t2, t2+1
  const float* sb = src + (size_t)b * CC * ROWS + PADL + t2;

  const float* W = Wt + layer * (CC * KK * 2 * CC);
  const float* hb = hid_b + layer * 2 * CC;

  float hx[2 * CC], hy[2 * CC];
#pragma unroll
  for (int co = 0; co < 2 * CC; ++co) {
    float bv = hb[co];
    hx[co] = bv;
    hy[co] = bv;
  }

  float xcx[CC], xcy[CC];   // center taps, reused for residual
#pragma unroll
  for (int ci = 0; ci < CC; ++ci) {
    const float* p = sb + (size_t)ci * ROWS;
    float2 x0 = ld2(p - 2 * D);               // tap k=0 for both t
    float2 x2 = ld2(p);                       // tap k=2 for both t
    float2 x1;
    if constexpr (D == 1) {
      x1 = make_float2(x0.y, x2.x);           // derive odd-offset tap, aligned
    } else {
      x1 = ld2(p - D);
    }
    xcx[ci] = x2.x;
    xcy[ci] = x2.y;
    const float* wk = W + ci * (KK * 2 * CC);
#pragma unroll
    for (int co = 0; co < 2 * CC; ++co) {
      float w = wk[co];
      hx[co] = fmaf(w, x0.x, hx[co]);
      hy[co] = fmaf(w, x0.y, hy[co]);
    }
#pragma unroll
    for (int co = 0; co < 2 * CC; ++co) {
      float w = wk[2 * CC + co];
      hx[co] = fmaf(w, x1.x, hx[co]);
      hy[co] = fmaf(w, x1.y, hy[co]);
    }
#pragma unroll
    for (int co = 0; co < 2 * CC; ++co) {
      float w = wk[4 * CC + co];
      hx[co] = fmaf(w, x2.x, hx[co]);
      hy[co] = fmaf(w, x2.y, hy[co]);
    }
  }

  // gated = tanh(h[:C]) * sigmoid(h[C:])
  float gx[CC], gy[CC];
#pragma unroll
  for (int c = 0; c < CC; ++c) {
    gx[c] = gate_fn(hx[c], hx[c + CC]);
    gy[c] = gate_fn(hy[c], hy[c + CC]);
  }

  // skip contribution (mix conv folded in)
  const float* mw = mix_w + layer * CC;
  float sx = 0.f, sy = 0.f;
#pragma unroll
  for (int c = 0; c < CC; ++c) {
    float w = mw[c];
    sx = fmaf(w, gx[c], sx);
    sy = fmaf(w, gy[c], sy);
  }
  size_t sidx = ((size_t)b << 15) + t2;
  float2 sk = ld2(skip + sidx);

  if (LAST) {
    float mb = mix_b[0];
    *reinterpret_cast<float2*>((float*)out + sidx) =
        make_float2(sk.x + sx + mb, sk.y + sy + mb);
  } else {
    *reinterpret_cast<float2*>(skip + sidx) = make_float2(sk.x + sx, sk.y + sy);

    // 1x1 res conv + residual
    const float* R = Rt + layer * (CC * CC);
    const float* rb = res_b + layer * CC;
    float ax[CC], ay[CC];
#pragma unroll
    for (int c = 0; c < CC; ++c) {
      float bv = rb[c];
      ax[c] = bv;
      ay[c] = bv;
    }
#pragma unroll
    for (int c2 = 0; c2 < CC; ++c2) {
      float g2x = gx[c2], g2y = gy[c2];
      const float* rr = R + c2 * CC;
#pragma unroll
      for (int c = 0; c < CC; ++c) {
        float w = rr[c];
        ax[c] = fmaf(w, g2x, ax[c]);
        ay[c] = fmaf(w, g2y, ay[c]);
      }
    }
    float* db = dst + (size_t)b * CC * ROWS + PADL + t2;
#pragma unroll
    for (int c = 0; c < CC; ++c) {
      *reinterpret_cast<float2*>(db + (size_t)c * ROWS) =
          make_float2(ax[c] + xcx[c], ay[c] + xcy[c]);
    }
  }
}

extern "C" void kernel_launch(void* const* d_in, const int* in_sizes, int n_in,
                              void* d_out, int out_size, void* d_ws, size_t ws_size,
                              hipStream_t stream) {
  const float* x     = (const float*)d_in[0];
  const float* in_w  = (const float*)d_in[1];
  const float* in_b  = (const float*)d_in[2];
  const float* hid_w = (const float*)d_in[3];
  const float* hid_b = (const float*)d_in[4];
  const float* res_w = (const float*)d_in[5];
  const float* res_b = (const float*)d_in[6];
  const float* mix_w = (const float*)d_in[7];
  const float* mix_b = (const float*)d_in[8];
  float* outp = (float*)d_out;

  float* ws = (float*)d_ws;
  float* s0   = ws;
  float* s1   = ws + STATE;
  float* skip = ws + 2 * STATE;                    // BB*TT floats
  float* Wt   = skip + (size_t)BB * TT;            // 24576 floats
  float* Rt   = Wt + LL * 2 * CC * CC * KK;        // 4096 floats

  wn_prep<<<112, 256, 0, stream>>>(hid_w, res_w, Wt, Rt);
  wn_zero_pads<<<256, 256, 0, stream>>>(s0, s1);
  wn_input<<<256, 256, 0, stream>>>(x, in_w, in_b, s0, skip);

  const float* src = s0;
  float* dst = s1;
  for (int i = 0; i < LL; ++i) {
    int d = 1 << (i & 7);
    if (i == LL - 1) {
      wn_layer<128, true><<<512, 256, 0, stream>>>(
          src, dst, Wt, hid_b, Rt, res_b, mix_w, mix_b, skip, outp, i);
    } else {
      switch (d) {
        case 1:   wn_layer<1,  false><<<512, 256, 0, stream>>>(src, dst, Wt, hid_b, Rt, res_b, mix_w, mix_b, skip, outp, i); break;
        case 2:   wn_layer<2,  false><<<512, 256, 0, stream>>>(src, dst, Wt, hid_b, Rt, res_b, mix_w, mix_b, skip, outp, i); break;
        case 4:   wn_layer<4,  false><<<512, 256, 0, stream>>>(src, dst, Wt, hid_b, Rt, res_b, mix_w, mix_b, skip, outp, i); break;
        case 8:   wn_layer<8,  false><<<512, 256, 0, stream>>>(src, dst, Wt, hid_b, Rt, res_b, mix_w, mix_b, skip, outp, i); break;
        case 16:  wn_layer<16, false><<<512, 256, 0, stream>>>(src, dst, Wt, hid_b, Rt, res_b, mix_w, mix_b, skip, outp, i); break;
        case 32:  wn_layer<32, false><<<512, 256, 0, stream>>>(src, dst, Wt, hid_b, Rt, res_b, mix_w, mix_b, skip, outp, i); break;
        case 64:  wn_layer<64, false><<<512, 256, 0, stream>>>(src, dst, Wt, hid_b, Rt, res_b, mix_w, mix_b, skip, outp, i); break;
        case 128: wn_layer<128,false><<<512, 256, 0, stream>>>(src, dst, Wt, hid_b, Rt, res_b, mix_w, mix_b, skip, outp, i); break;
      }
    }
    const float* tmp = dst;
    dst = (float*)src;
    src = tmp;
  }
}

// Round 4
// 153.908 us; speedup vs baseline: 3.2648x; 2.5929x over previous
//
#include <hip/hip_runtime.h>

#define CC 16
#define LL 16
#define TT 32768
#define BB 8
#define PADT 256                      // left pad in t slots (= 2*max_dilation)
#define RT (PADT + TT)                // 33024 t-slots per batch row

typedef unsigned int uint;
typedef unsigned short ushort;
typedef uint  u32x2 __attribute__((ext_vector_type(2)));
typedef float f32x4 __attribute__((ext_vector_type(4)));
typedef short s16x8 __attribute__((ext_vector_type(8)));   // 8 bf16 (4 VGPRs)

__device__ __forceinline__ ushort f2bf(float f) {
  uint u = __float_as_uint(f);
  return (ushort)((u + 0x7FFFu + ((u >> 16) & 1u)) >> 16);   // RNE
}
__device__ __forceinline__ float bf2f(ushort h) {
  return __uint_as_float(((uint)h) << 16);
}

// ---------------- prep: pack weights into MFMA fragment order, zero pads ----
// WA[((l*2+cot)*2+frag)*64 + lane][j] : A-frag bf16, row co = cot*16+(lane&15)
//   frag0: k=(g<2?0:1), ci=(g&1)*8+j ; frag1: g<2 -> k=2, ci=g*8+j ; else 0
// RA[l*64+lane][j] : res A-frag, row c=lane&15; g<2 -> c2=g*8+j ; else 0
__global__ __launch_bounds__(256) void wn_prep(
    const float* __restrict__ hw, const float* __restrict__ rw,
    ushort* __restrict__ WA, ushort* __restrict__ RA,
    ushort* __restrict__ s0, ushort* __restrict__ s1) {
  int tid = blockIdx.x * 256 + threadIdx.x;      // 73728 total
  if (tid < 32768) {
    int j = tid & 7, lane = (tid >> 3) & 63, frag = (tid >> 9) & 1;
    int cot = (tid >> 10) & 1, l = tid >> 11;
    int co = cot * 16 + (lane & 15), g = lane >> 4;
    float v = 0.f;
    if (frag == 0) {
      int k = (g < 2) ? 0 : 1, ci = (g & 1) * 8 + j;
      v = hw[((l * 32 + co) * 16 + ci) * 3 + k];
    } else if (g < 2) {
      int ci = g * 8 + j;
      v = hw[((l * 32 + co) * 16 + ci) * 3 + 2];
    }
    WA[tid] = f2bf(v);
  } else if (tid < 40960) {
    int r = tid - 32768;
    int j = r & 7, lane = (r >> 3) & 63, l = r >> 9;
    int c = lane & 15, g = lane >> 4;
    float v = 0.f;
    if (g < 2) v = rw[(l * 16 + c) * 16 + (g * 8 + j)];
    RA[r] = f2bf(v);
  } else {
    int r = tid - 40960;                         // 32768 uint writes
    int buf = r >> 14, q = r & 16383;            // 8 b * 2048 uints
    int b = q >> 11, rem = q & 2047;             // pad = 256 t * 8 uints
    uint* p = (uint*)(buf ? s1 : s0) + (size_t)b * RT * 8 + rem;
    *p = 0u;
  }
}

// ---------------- input 1x1 conv -> bf16 state [b][t][ci], skip init --------
__global__ __launch_bounds__(256) void wn_in(
    const float* __restrict__ x, const float* __restrict__ in_w,
    const float* __restrict__ in_b, ushort* __restrict__ s0,
    float* __restrict__ skip) {
  int tid = blockIdx.x * 256 + threadIdx.x;      // BB*TT
  int b = tid >> 15, t = tid & (TT - 1);
  float xv = x[tid];
  uint pk[8];
#pragma unroll
  for (int c = 0; c < 8; ++c) {
    float a = fmaf(in_w[2 * c], xv, in_b[2 * c]);
    float d = fmaf(in_w[2 * c + 1], xv, in_b[2 * c + 1]);
    pk[c] = (uint)f2bf(a) | ((uint)f2bf(d) << 16);
  }
  uint* p = (uint*)s0 + ((size_t)b * RT + PADT + t) * 8;
  uint4 v0 = make_uint4(pk[0], pk[1], pk[2], pk[3]);
  uint4 v1 = make_uint4(pk[4], pk[5], pk[6], pk[7]);
  *(uint4*)p = v0;
  *(uint4*)(p + 4) = v1;
  skip[tid] = 0.f;
}

// ---------------- one fused layer: conv MFMA + gate + skip + res MFMA -------
template <int D, bool LAST>
__global__ __launch_bounds__(256) void wn_layer(
    const ushort* __restrict__ src, ushort* __restrict__ dst,
    const ushort* __restrict__ WA, const ushort* __restrict__ RA,
    const float* __restrict__ hid_b, const float* __restrict__ res_b,
    const float* __restrict__ mix_w, const float* __restrict__ mix_b,
    float* __restrict__ skip, float* __restrict__ outp, int layer) {
  __shared__ ushort lds[4][16][16];
  int lane = threadIdx.x & 63, w = threadIdx.x >> 6;
  int col = lane & 15, g = lane >> 4;
  int b = blockIdx.x >> 7, chunk = blockIdx.x & 127;
  int t0 = chunk * 256 + w * 64;                 // wave strip: 4 groups of 16 t

  // A-fragments (held across iterations)
  const s16x8* wa = (const s16x8*)(WA + (size_t)layer * 2 * 2 * 64 * 8);
  s16x8 a00 = wa[lane];          // co-tile 0, K 0-31  (k=0,1)
  s16x8 a01 = wa[64 + lane];     // co-tile 0, K 32-63 (k=2 | zeros)
  s16x8 a10 = wa[128 + lane];    // co-tile 1, K 0-31
  s16x8 a11 = wa[192 + lane];
  s16x8 ra  = *(const s16x8*)(RA + (size_t)layer * 64 * 8 + lane * 8);

  f32x4 b0 = *(const f32x4*)(hid_b + layer * 32 + g * 4);
  f32x4 b1 = *(const f32x4*)(hid_b + layer * 32 + 16 + g * 4);
  f32x4 mw4 = *(const f32x4*)(mix_w + layer * 16 + g * 4);
  f32x4 br = {0.f, 0.f, 0.f, 0.f};
  if (!LAST) br = *(const f32x4*)(res_b + layer * 16 + g * 4);
  float mb = LAST ? mix_b[0] : 0.f;

  const ushort* sb = src + (size_t)b * RT * 16;
  int toff0 = (g < 2) ? 2 * D : D;               // frag0: k=0 or k=1 tap
  const ushort* pf0 = sb + (size_t)(PADT + t0 + col - toff0) * 16 + (g & 1) * 8;
  const ushort* pf1 = sb + (size_t)(PADT + t0 + col) * 16 + g * 8;  // g<2 only
  const ushort* pc  = sb + (size_t)(PADT + t0 + col) * 16 + g * 4;  // center taps
  ushort* pdst = dst + (size_t)b * RT * 16 + (size_t)(PADT + t0 + col) * 16 + g * 4;
  float* psk = skip + (size_t)b * TT + t0 + col;
  float* pout = outp + (size_t)b * TT + t0 + col;

#pragma unroll
  for (int it = 0; it < 4; ++it) {
    s16x8 bf0 = *(const s16x8*)(pf0 + it * 256);
    s16x8 bf1 = {0, 0, 0, 0, 0, 0, 0, 0};
    if (g < 2) bf1 = *(const s16x8*)(pf1 + it * 256);

    f32x4 acc0 = b0, acc1 = b1;
    acc0 = __builtin_amdgcn_mfma_f32_16x16x32_bf16(a00, bf0, acc0, 0, 0, 0);
    acc0 = __builtin_amdgcn_mfma_f32_16x16x32_bf16(a01, bf1, acc0, 0, 0, 0);
    acc1 = __builtin_amdgcn_mfma_f32_16x16x32_bf16(a10, bf0, acc1, 0, 0, 0);
    acc1 = __builtin_amdgcn_mfma_f32_16x16x32_bf16(a11, bf1, acc1, 0, 0, 0);

    // gated = tanh(acc0) * sigmoid(acc1)   (fragment-local pairs)
    float gg[4];
#pragma unroll
    for (int i = 0; i < 4; ++i) {
      float a = fminf(fmaxf(acc0[i], -15.f), 15.f);
      float ea = __expf(2.f * a);
      float th = 1.f - 2.f * __builtin_amdgcn_rcpf(ea + 1.f);
      float bq = fminf(fmaxf(acc1[i], -30.f), 30.f);
      float sg = __builtin_amdgcn_rcpf(1.f + __expf(-bq));
      gg[i] = th * sg;
    }

    // skip (mix conv folded): reduce over the 4 row-groups
    float s = gg[0] * mw4[0];
    s = fmaf(gg[1], mw4[1], s);
    s = fmaf(gg[2], mw4[2], s);
    s = fmaf(gg[3], mw4[3], s);
    s += __shfl_xor(s, 16);
    s += __shfl_xor(s, 32);
    if (g == 0) {
      float sv = psk[it * 16] + s;
      if (LAST) pout[it * 16] = sv + mb;
      else      psk[it * 16] = sv;
    }

    if (!LAST) {
      // gates -> LDS (bf16 [t][c2]) -> res-conv B-fragment (wave-synchronous)
      uint u0 = (uint)f2bf(gg[0]) | ((uint)f2bf(gg[1]) << 16);
      uint u1 = (uint)f2bf(gg[2]) | ((uint)f2bf(gg[3]) << 16);
      u32x2 gv = {u0, u1};
      *(u32x2*)&lds[w][col][g * 4] = gv;
      asm volatile("s_waitcnt lgkmcnt(0)" ::: "memory");
      __builtin_amdgcn_sched_barrier(0);
      s16x8 gb = {0, 0, 0, 0, 0, 0, 0, 0};
      if (g < 2) gb = *(const s16x8*)&lds[w][col][g * 8];

      f32x4 accr = br;
      accr = __builtin_amdgcn_mfma_f32_16x16x32_bf16(ra, gb, accr, 0, 0, 0);

      u32x2 cv = *(const u32x2*)(pc + it * 256);
      float r0 = accr[0] + bf2f((ushort)(cv[0] & 0xffff));
      float r1 = accr[1] + bf2f((ushort)(cv[0] >> 16));
      float r2 = accr[2] + bf2f((ushort)(cv[1] & 0xffff));
      float r3 = accr[3] + bf2f((ushort)(cv[1] >> 16));
      uint o0 = (uint)f2bf(r0) | ((uint)f2bf(r1) << 16);
      uint o1 = (uint)f2bf(r2) | ((uint)f2bf(r3) << 16);
      u32x2 ov = {o0, o1};
      *(u32x2*)(pdst + it * 256) = ov;
    }
  }
}

extern "C" void kernel_launch(void* const* d_in, const int* in_sizes, int n_in,
                              void* d_out, int out_size, void* d_ws, size_t ws_size,
                              hipStream_t stream) {
  const float* x     = (const float*)d_in[0];
  const float* in_w  = (const float*)d_in[1];
  const float* in_b  = (const float*)d_in[2];
  const float* hid_w = (const float*)d_in[3];
  const float* hid_b = (const float*)d_in[4];
  const float* res_w = (const float*)d_in[5];
  const float* res_b = (const float*)d_in[6];
  const float* mix_w = (const float*)d_in[7];
  const float* mix_b = (const float*)d_in[8];
  float* outp = (float*)d_out;

  const size_t SROW = (size_t)BB * RT * 16;          // ushorts per state buffer
  ushort* s0   = (ushort*)d_ws;
  ushort* s1   = s0 + SROW;
  float*  skip = (float*)(s1 + SROW);
  ushort* WA   = (ushort*)(skip + (size_t)BB * TT);
  ushort* RA   = WA + 32768;

  wn_prep<<<288, 256, 0, stream>>>(hid_w, res_w, WA, RA, s0, s1);
  wn_in<<<1024, 256, 0, stream>>>(x, in_w, in_b, s0, skip);

  const ushort* src = s0;
  ushort* dst = s1;
  for (int i = 0; i < LL; ++i) {
    int d = 1 << (i & 7);
    if (i == LL - 1) {
      wn_layer<128, true><<<1024, 256, 0, stream>>>(
          src, dst, WA, RA, hid_b, res_b, mix_w, mix_b, skip, outp, i);
    } else {
      switch (d) {
        case 1:   wn_layer<1,  false><<<1024, 256, 0, stream>>>(src, dst, WA, RA, hid_b, res_b, mix_w, mix_b, skip, outp, i); break;
        case 2:   wn_layer<2,  false><<<1024, 256, 0, stream>>>(src, dst, WA, RA, hid_b, res_b, mix_w, mix_b, skip, outp, i); break;
        case 4:   wn_layer<4,  false><<<1024, 256, 0, stream>>>(src, dst, WA, RA, hid_b, res_b, mix_w, mix_b, skip, outp, i); break;
        case 8:   wn_layer<8,  false><<<1024, 256, 0, stream>>>(src, dst, WA, RA, hid_b, res_b, mix_w, mix_b, skip, outp, i); break;
        case 16:  wn_layer<16, false><<<1024, 256, 0, stream>>>(src, dst, WA, RA, hid_b, res_b, mix_w, mix_b, skip, outp, i); break;
        case 32:  wn_layer<32, false><<<1024, 256, 0, stream>>>(src, dst, WA, RA, hid_b, res_b, mix_w, mix_b, skip, outp, i); break;
        case 64:  wn_layer<64, false><<<1024, 256, 0, stream>>>(src, dst, WA, RA, hid_b, res_b, mix_w, mix_b, skip, outp, i); break;
        case 128: wn_layer<128,false><<<1024, 256, 0, stream>>>(src, dst, WA, RA, hid_b, res_b, mix_w, mix_b, skip, outp, i); break;
      }
    }
    const ushort* tmp = dst;
    dst = (ushort*)src;
    src = tmp;
  }
}

// Round 5
// 140.004 us; speedup vs baseline: 3.5890x; 1.0993x over previous
//
#include <hip/hip_runtime.h>

#define CC 16
#define LL 16
#define TT 32768
#define BB 8
#define PADT 256                      // left pad in t slots (= 2*max_dilation)
#define RT (PADT + TT)                // 33024 t-slots per batch row

typedef unsigned int uint;
typedef unsigned short ushort;
typedef uint  u32x2 __attribute__((ext_vector_type(2)));
typedef uint  u32x4 __attribute__((ext_vector_type(4)));
typedef float f32x4 __attribute__((ext_vector_type(4)));
typedef short s16x8 __attribute__((ext_vector_type(8)));   // 8 bf16 (4 VGPRs)

__device__ __forceinline__ ushort f2bf(float f) {
  uint u = __float_as_uint(f);
  return (ushort)((u + 0x7FFFu + ((u >> 16) & 1u)) >> 16);   // RNE
}
__device__ __forceinline__ float bf2f(ushort h) {
  return __uint_as_float(((uint)h) << 16);
}

// ---------------- prep: pack weights into MFMA fragment order, zero pads ----
// WA[((l*2+cot)*2+frag)*64 + lane][j] : A-frag bf16, row co = cot*16+(lane&15)
//   frag0: k=(g<2?0:1), ci=(g&1)*8+j ; frag1: g<2 -> k=2, ci=g*8+j ; else 0
// RA[l*64+lane][j] : res A-frag, row c=lane&15; g<2 -> c2=g*8+j ; else 0
__global__ __launch_bounds__(256) void wn_prep(
    const float* __restrict__ hw, const float* __restrict__ rw,
    ushort* __restrict__ WA, ushort* __restrict__ RA,
    ushort* __restrict__ s0, ushort* __restrict__ s1) {
  int tid = blockIdx.x * 256 + threadIdx.x;      // 73728 total
  if (tid < 32768) {
    int j = tid & 7, lane = (tid >> 3) & 63, frag = (tid >> 9) & 1;
    int cot = (tid >> 10) & 1, l = tid >> 11;
    int co = cot * 16 + (lane & 15), g = lane >> 4;
    float v = 0.f;
    if (frag == 0) {
      int k = (g < 2) ? 0 : 1, ci = (g & 1) * 8 + j;
      v = hw[((l * 32 + co) * 16 + ci) * 3 + k];
    } else if (g < 2) {
      int ci = g * 8 + j;
      v = hw[((l * 32 + co) * 16 + ci) * 3 + 2];
    }
    WA[tid] = f2bf(v);
  } else if (tid < 40960) {
    int r = tid - 32768;
    int j = r & 7, lane = (r >> 3) & 63, l = r >> 9;
    int c = lane & 15, g = lane >> 4;
    float v = 0.f;
    if (g < 2) v = rw[(l * 16 + c) * 16 + (g * 8 + j)];
    RA[r] = f2bf(v);
  } else {
    int r = tid - 40960;                         // 32768 uint writes
    int buf = r >> 14, q = r & 16383;            // 8 b * 2048 uints
    int b = q >> 11, rem = q & 2047;             // pad = 256 t * 8 uints
    uint* p = (uint*)(buf ? s1 : s0) + (size_t)b * RT * 8 + rem;
    *p = 0u;
  }
}

// ---------------- input 1x1 conv -> bf16 state [b][t][ci], skip init --------
__global__ __launch_bounds__(256) void wn_in(
    const float* __restrict__ x, const float* __restrict__ in_w,
    const float* __restrict__ in_b, ushort* __restrict__ s0,
    float* __restrict__ skip) {
  // XCD<->batch affinity: blocks 0..127 of each XCD cover one b
  int wid = (blockIdx.x & 7) * 128 + (blockIdx.x >> 3);
  int tid = wid * 256 + threadIdx.x;             // BB*TT
  int b = tid >> 15, t = tid & (TT - 1);
  float xv = x[tid];
  uint pk[8];
#pragma unroll
  for (int c = 0; c < 8; ++c) {
    float a = fmaf(in_w[2 * c], xv, in_b[2 * c]);
    float d = fmaf(in_w[2 * c + 1], xv, in_b[2 * c + 1]);
    pk[c] = (uint)f2bf(a) | ((uint)f2bf(d) << 16);
  }
  uint* p = (uint*)s0 + ((size_t)b * RT + PADT + t) * 8;
  uint4 v0 = make_uint4(pk[0], pk[1], pk[2], pk[3]);
  uint4 v1 = make_uint4(pk[4], pk[5], pk[6], pk[7]);
  *(uint4*)p = v0;
  *(uint4*)(p + 4) = v1;
  skip[tid] = 0.f;
}

// ---------------- one fused layer: conv MFMA + gate + skip + res MFMA -------
template <int D, bool LAST>
__global__ __launch_bounds__(256) void wn_layer(
    const ushort* __restrict__ src, ushort* __restrict__ dst,
    const ushort* __restrict__ WA, const ushort* __restrict__ RA,
    const float* __restrict__ hid_b, const float* __restrict__ res_b,
    const float* __restrict__ mix_w, const float* __restrict__ mix_b,
    float* __restrict__ skip, float* __restrict__ outp, int layer) {
  // XCD<->batch affinity: wid in [b*256, b*256+256) lands on XCD b
  int wid = (blockIdx.x & 7) * 256 + (blockIdx.x >> 3);
  int lane = threadIdx.x & 63, w = threadIdx.x >> 6;
  int col = lane & 15, g = lane >> 4;
  int b = wid >> 8, chunk = wid & 255;
  int t0 = chunk * 128 + w * 32;                 // wave strip: 2 groups of 16 t

  // A-fragments (held across iterations)
  const s16x8* wa = (const s16x8*)(WA + (size_t)layer * 2 * 2 * 64 * 8);
  s16x8 a00 = wa[lane];          // co-tile 0, K 0-31  (k=0,1)
  s16x8 a01 = wa[64 + lane];     // co-tile 0, K 32-63 (k=2 | zeros)
  s16x8 a10 = wa[128 + lane];    // co-tile 1, K 0-31
  s16x8 a11 = wa[192 + lane];
  s16x8 ra  = *(const s16x8*)(RA + (size_t)layer * 64 * 8 + lane * 8);

  f32x4 b0 = *(const f32x4*)(hid_b + layer * 32 + g * 4);
  f32x4 b1 = *(const f32x4*)(hid_b + layer * 32 + 16 + g * 4);
  f32x4 mw4 = *(const f32x4*)(mix_w + layer * 16 + g * 4);
  f32x4 br = {0.f, 0.f, 0.f, 0.f};
  if (!LAST) br = *(const f32x4*)(res_b + layer * 16 + g * 4);
  float mb = LAST ? mix_b[0] : 0.f;

  const ushort* sb = src + (size_t)b * RT * 16;
  int toff0 = (g < 2) ? 2 * D : D;               // frag0: k=0 or k=1 tap
  const ushort* pf0 = sb + (size_t)(PADT + t0 + col - toff0) * 16 + (g & 1) * 8;
  const ushort* pf1 = sb + (size_t)(PADT + t0 + col) * 16 + g * 8;  // g<2 only
  const ushort* pc  = sb + (size_t)(PADT + t0 + col) * 16 + g * 4;  // center taps
  ushort* pdst = dst + (size_t)b * RT * 16 + (size_t)(PADT + t0 + col) * 16 + g * 4;
  float* psk = skip + (size_t)b * TT + t0 + col;
  float* pout = outp + (size_t)b * TT + t0 + col;

#pragma unroll
  for (int it = 0; it < 2; ++it) {
    s16x8 bf0 = *(const s16x8*)(pf0 + it * 256);
    s16x8 bf1 = {0, 0, 0, 0, 0, 0, 0, 0};
    if (g < 2) bf1 = *(const s16x8*)(pf1 + it * 256);

    f32x4 acc0 = b0, acc1 = b1;
    acc0 = __builtin_amdgcn_mfma_f32_16x16x32_bf16(a00, bf0, acc0, 0, 0, 0);
    acc0 = __builtin_amdgcn_mfma_f32_16x16x32_bf16(a01, bf1, acc0, 0, 0, 0);
    acc1 = __builtin_amdgcn_mfma_f32_16x16x32_bf16(a10, bf0, acc1, 0, 0, 0);
    acc1 = __builtin_amdgcn_mfma_f32_16x16x32_bf16(a11, bf1, acc1, 0, 0, 0);

    // gated = tanh(acc0) * sigmoid(acc1)   (fragment-local pairs)
    float gg[4];
#pragma unroll
    for (int i = 0; i < 4; ++i) {
      float a = fminf(fmaxf(acc0[i], -15.f), 15.f);
      float ea = __expf(2.f * a);
      float th = 1.f - 2.f * __builtin_amdgcn_rcpf(ea + 1.f);
      float bq = fminf(fmaxf(acc1[i], -30.f), 30.f);
      float sg = __builtin_amdgcn_rcpf(1.f + __expf(-bq));
      gg[i] = th * sg;
    }

    // skip (mix conv folded): reduce over the 4 row-groups
    float s = gg[0] * mw4[0];
    s = fmaf(gg[1], mw4[1], s);
    s = fmaf(gg[2], mw4[2], s);
    s = fmaf(gg[3], mw4[3], s);
    s += __shfl_xor(s, 16);
    s += __shfl_xor(s, 32);
    if (g == 0) {
      float sv = psk[it * 16] + s;
      if (LAST) pout[it * 16] = sv + mb;
      else      psk[it * 16] = sv;
    }

    if (!LAST) {
      // res-conv B-fragment via cross-lane regroup (no LDS, no fence):
      // dest lane (g,col), g<2, needs c2=g*8+j -> gates of lanes (2g,col),(2g+1,col)
      uint u0 = (uint)f2bf(gg[0]) | ((uint)f2bf(gg[1]) << 16);
      uint u1 = (uint)f2bf(gg[2]) | ((uint)f2bf(gg[3]) << 16);
      int sA = (((g << 1) & 3) << 4) + col;
      int sB = ((((g << 1) | 1) & 3) << 4) + col;
      uint w0 = __shfl(u0, sA), w1 = __shfl(u1, sA);
      uint w2 = __shfl(u0, sB), w3 = __shfl(u1, sB);
      u32x4 gw = {w0, w1, w2, w3};
      if (g >= 2) gw = (u32x4){0, 0, 0, 0};
      s16x8 gb = __builtin_bit_cast(s16x8, gw);

      f32x4 accr = br;
      accr = __builtin_amdgcn_mfma_f32_16x16x32_bf16(ra, gb, accr, 0, 0, 0);

      u32x2 cv = *(const u32x2*)(pc + it * 256);
      float r0 = accr[0] + bf2f((ushort)(cv[0] & 0xffff));
      float r1 = accr[1] + bf2f((ushort)(cv[0] >> 16));
      float r2 = accr[2] + bf2f((ushort)(cv[1] & 0xffff));
      float r3 = accr[3] + bf2f((ushort)(cv[1] >> 16));
      uint o0 = (uint)f2bf(r0) | ((uint)f2bf(r1) << 16);
      uint o1 = (uint)f2bf(r2) | ((uint)f2bf(r3) << 16);
      u32x2 ov = {o0, o1};
      *(u32x2*)(pdst + it * 256) = ov;
    }
  }
}

extern "C" void kernel_launch(void* const* d_in, const int* in_sizes, int n_in,
                              void* d_out, int out_size, void* d_ws, size_t ws_size,
                              hipStream_t stream) {
  const float* x     = (const float*)d_in[0];
  const float* in_w  = (const float*)d_in[1];
  const float* in_b  = (const float*)d_in[2];
  const float* hid_w = (const float*)d_in[3];
  const float* hid_b = (const float*)d_in[4];
  const float* res_w = (const float*)d_in[5];
  const float* res_b = (const float*)d_in[6];
  const float* mix_w = (const float*)d_in[7];
  const float* mix_b = (const float*)d_in[8];
  float* outp = (float*)d_out;

  const size_t SROW = (size_t)BB * RT * 16;          // ushorts per state buffer
  ushort* s0   = (ushort*)d_ws;
  ushort* s1   = s0 + SROW;
  float*  skip = (float*)(s1 + SROW);
  ushort* WA   = (ushort*)(skip + (size_t)BB * TT);
  ushort* RA   = WA + 32768;

  wn_prep<<<288, 256, 0, stream>>>(hid_w, res_w, WA, RA, s0, s1);
  wn_in<<<1024, 256, 0, stream>>>(x, in_w, in_b, s0, skip);

  const ushort* src = s0;
  ushort* dst = s1;
  for (int i = 0; i < LL; ++i) {
    int d = 1 << (i & 7);
    if (i == LL - 1) {
      wn_layer<128, true><<<2048, 256, 0, stream>>>(
          src, dst, WA, RA, hid_b, res_b, mix_w, mix_b, skip, outp, i);
    } else {
      switch (d) {
        case 1:   wn_layer<1,  false><<<2048, 256, 0, stream>>>(src, dst, WA, RA, hid_b, res_b, mix_w, mix_b, skip, outp, i); break;
        case 2:   wn_layer<2,  false><<<2048, 256, 0, stream>>>(src, dst, WA, RA, hid_b, res_b, mix_w, mix_b, skip, outp, i); break;
        case 4:   wn_layer<4,  false><<<2048, 256, 0, stream>>>(src, dst, WA, RA, hid_b, res_b, mix_w, mix_b, skip, outp, i); break;
        case 8:   wn_layer<8,  false><<<2048, 256, 0, stream>>>(src, dst, WA, RA, hid_b, res_b, mix_w, mix_b, skip, outp, i); break;
        case 16:  wn_layer<16, false><<<2048, 256, 0, stream>>>(src, dst, WA, RA, hid_b, res_b, mix_w, mix_b, skip, outp, i); break;
        case 32:  wn_layer<32, false><<<2048, 256, 0, stream>>>(src, dst, WA, RA, hid_b, res_b, mix_w, mix_b, skip, outp, i); break;
        case 64:  wn_layer<64, false><<<2048, 256, 0, stream>>>(src, dst, WA, RA, hid_b, res_b, mix_w, mix_b, skip, outp, i); break;
        case 128: wn_layer<128,false><<<2048, 256, 0, stream>>>(src, dst, WA, RA, hid_b, res_b, mix_w, mix_b, skip, outp, i); break;
      }
    }
    const ushort* tmp = dst;
    dst = (ushort*)src;
    src = tmp;
  }
}

// Round 7
// 138.309 us; speedup vs baseline: 3.6330x; 1.0123x over previous
//
#include <hip/hip_runtime.h>

#define CC 16
#define LL 16
#define TT 32768
#define BB 8
#define TILE 1024                 // output t per block
#define BASEI 1040                // LDS row u = tau + BASEI (tau in [-1040,1024))
#define NSLOT 2064                // rows per buffer
#define BUFB (NSLOT * 32)         // bytes per buffer (66048)

typedef unsigned int uint;
typedef unsigned short ushort;
typedef uint  u32x2 __attribute__((ext_vector_type(2)));
typedef uint  u32x4 __attribute__((ext_vector_type(4)));
typedef float f32x4 __attribute__((ext_vector_type(4)));
typedef short s16x8 __attribute__((ext_vector_type(8)));   // 8 bf16

// floor16 of output-span start s_{i+1} (suffix sums of 2*d), per layer
__device__ const int OST_TAB[LL] = {-1024,-1024,-1008,-992,-960,-896,-768,-512,
                                    -512,-512,-496,-480,-448,-384,-256,0};

__device__ __forceinline__ ushort f2bf(float f) {
  uint u = __float_as_uint(f);
  return (ushort)((u + 0x7FFFu + ((u >> 16) & 1u)) >> 16);   // RNE
}
__device__ __forceinline__ float bf2f(ushort h) {
  return __uint_as_float(((uint)h) << 16);
}
__device__ __forceinline__ f32x4 mfma16(s16x8 a, s16x8 b, f32x4 c) {
  return __builtin_amdgcn_mfma_f32_16x16x32_bf16(a, b, c, 0, 0, 0);
}
// LDS byte-address swizzle: XOR 16B-slot bits (4-6) with row bits 2-4.
// Globally bijective (row bits 2-4 live untouched in addr bits 7-9); 16B/8B
// chunks stay contiguous. Applied identically at all access sites.
__device__ __forceinline__ int swz(int u, int o) {
  return ((u << 5) + o) ^ ((u & 28) << 2);
}

// ---------------- prep: pack weights into MFMA fragment order ----------------
// WA[((l*2+cot)*2+frag)*64 + lane][j]: frag0: k=(g<2?0:1), ci=(g&1)*8+j
//                                     frag1: g<2 -> k=2, ci=g*8+j ; else 0
// RA[l*64+lane][j]: row c=lane&15; g<2 -> c2=g*8+j ; else 0
__global__ __launch_bounds__(256) void wn_prep(
    const float* __restrict__ hw, const float* __restrict__ rw,
    ushort* __restrict__ WA, ushort* __restrict__ RA) {
  int tid = blockIdx.x * 256 + threadIdx.x;      // 40960 total
  if (tid < 32768) {
    int j = tid & 7, lane = (tid >> 3) & 63, frag = (tid >> 9) & 1;
    int cot = (tid >> 10) & 1, l = tid >> 11;
    int co = cot * 16 + (lane & 15), g = lane >> 4;
    float v = 0.f;
    if (frag == 0) {
      int k = (g < 2) ? 0 : 1, ci = (g & 1) * 8 + j;
      v = hw[((l * 32 + co) * 16 + ci) * 3 + k];
    } else if (g < 2) {
      int ci = g * 8 + j;
      v = hw[((l * 32 + co) * 16 + ci) * 3 + 2];
    }
    WA[tid] = f2bf(v);
  } else if (tid < 40960) {
    int r = tid - 32768;
    int j = r & 7, lane = (r >> 3) & 63, l = r >> 9;
    int c = lane & 15, g = lane >> 4;
    float v = 0.f;
    if (g < 2) v = rw[(l * 16 + c) * 16 + (g * 8 + j)];
    RA[r] = f2bf(v);
  }
}

// ---------------- fully fused WaveNet: 16 layers in one launch ----------------
__global__ __launch_bounds__(1024, 4) void wn_fused(
    const float* __restrict__ x, const float* __restrict__ in_w,
    const float* __restrict__ in_b,
    const ushort* __restrict__ WA, const ushort* __restrict__ RA,
    const float* __restrict__ hid_b, const float* __restrict__ res_b,
    const float* __restrict__ mix_w, const float* __restrict__ mix_b,
    float* __restrict__ outp) {
  __shared__ ushort sbuf[2][NSLOT * 16];   // 2 x 66048 B, swizzled [t][16ch] bf16
  __shared__ float skipL[TILE];            // fp32 skip accumulator

  int tid = threadIdx.x;
  int b = blockIdx.x & 7, tile = blockIdx.x >> 3;   // XCD<->batch affinity
  int t0 = tile * TILE;
  char* lds = (char*)sbuf;

  // ---- stage: input 1x1 conv into buf0 over tau in [-1040, 1024) ----
  for (int r = tid; r < NSLOT; r += 1024) {
    int t = t0 + r - BASEI;
    uint pk[8];
    if (t >= 0) {
      float xv = x[b * TT + t];
#pragma unroll
      for (int c = 0; c < 8; ++c) {
        float lo = fmaf(in_w[2 * c], xv, in_b[2 * c]);
        float hi = fmaf(in_w[2 * c + 1], xv, in_b[2 * c + 1]);
        pk[c] = (uint)f2bf(lo) | ((uint)f2bf(hi) << 16);
      }
    } else {
#pragma unroll
      for (int c = 0; c < 8; ++c) pk[c] = 0u;     // causal zero pad (ref: layer-0 input pad)
    }
    *(u32x4*)(lds + swz(r, 0))  = (u32x4){pk[0], pk[1], pk[2], pk[3]};
    *(u32x4*)(lds + swz(r, 16)) = (u32x4){pk[4], pk[5], pk[6], pk[7]};
  }
  skipL[tid] = 0.f;
  __syncthreads();

  int lane = tid & 63, w = tid >> 6;
  int col = lane & 15, g = lane >> 4;
  int cur = 0;

  for (int i = 0; i < LL; ++i) {
    int D = 1 << (i & 7);
    int ost = OST_TAB[i];
    int ng = (TILE - ost) >> 4;
    bool last = (i == LL - 1);

    const s16x8* wa = (const s16x8*)(WA + (size_t)i * 2048);
    s16x8 a00 = wa[lane];
    s16x8 a01 = wa[64 + lane];
    s16x8 a10 = wa[128 + lane];
    s16x8 a11 = wa[192 + lane];
    s16x8 ra  = *(const s16x8*)(RA + (size_t)i * 512 + lane * 8);

    f32x4 b0  = *(const f32x4*)(hid_b + i * 32 + g * 4);
    f32x4 b1  = *(const f32x4*)(hid_b + i * 32 + 16 + g * 4);
    f32x4 mw4 = *(const f32x4*)(mix_w + i * 16 + g * 4);
    f32x4 br  = {0.f, 0.f, 0.f, 0.f};
    if (!last) br = *(const f32x4*)(res_b + i * 16 + g * 4);

    char* rbuf = lds + cur * BUFB;
    char* wbuf = lds + (cur ^ 1) * BUFB;
    int toff0 = (g < 2) ? 2 * D : D;

    auto body = [&](int gi) {
      int tb = ost + (gi << 4);
      int u = tb + col + BASEI;
      s16x8 bf0 = *(const s16x8*)(rbuf + swz(u - toff0, (g & 1) * 16));
      s16x8 bf1 = {0, 0, 0, 0, 0, 0, 0, 0};
      if (g < 2) bf1 = *(const s16x8*)(rbuf + swz(u, g * 16));

      f32x4 acc0 = b0, acc1 = b1;
      acc0 = mfma16(a00, bf0, acc0);
      acc0 = mfma16(a01, bf1, acc0);
      acc1 = mfma16(a10, bf0, acc1);
      acc1 = mfma16(a11, bf1, acc1);

      float gg[4];
#pragma unroll
      for (int q = 0; q < 4; ++q) {
        float a = fminf(fmaxf(acc0[q], -15.f), 15.f);
        float ea = __expf(2.f * a);
        float th = 1.f - 2.f * __builtin_amdgcn_rcpf(ea + 1.f);
        float bq = fminf(fmaxf(acc1[q], -30.f), 30.f);
        float sg = __builtin_amdgcn_rcpf(1.f + __expf(-bq));
        gg[q] = th * sg;
      }

      // skip (mix conv folded), only for output-tile region
      float s = gg[0] * mw4[0];
      s = fmaf(gg[1], mw4[1], s);
      s = fmaf(gg[2], mw4[2], s);
      s = fmaf(gg[3], mw4[3], s);
      s += __shfl_xor(s, 16);
      s += __shfl_xor(s, 32);
      if (tb >= 0 && g == 0) skipL[tb + col] += s;

      if (!last) {
        // res-conv B-fragment via cross-lane regroup
        uint u0 = (uint)f2bf(gg[0]) | ((uint)f2bf(gg[1]) << 16);
        uint u1 = (uint)f2bf(gg[2]) | ((uint)f2bf(gg[3]) << 16);
        int sA = (((g << 1) & 3) << 4) + col;
        int sB = ((((g << 1) | 1) & 3) << 4) + col;
        uint w0 = __shfl(u0, sA), w1 = __shfl(u1, sA);
        uint w2 = __shfl(u0, sB), w3 = __shfl(u1, sB);
        u32x4 gw = {w0, w1, w2, w3};
        if (g >= 2) gw = (u32x4){0, 0, 0, 0};
        s16x8 gb = __builtin_bit_cast(s16x8, gw);

        f32x4 accr = br;
        accr = mfma16(ra, gb, accr);

        u32x2 cv = *(const u32x2*)(rbuf + swz(u, g * 8));   // center taps
        float r0 = accr[0] + bf2f((ushort)(cv[0] & 0xffff));
        float r1 = accr[1] + bf2f((ushort)(cv[0] >> 16));
        float r2 = accr[2] + bf2f((ushort)(cv[1] & 0xffff));
        float r3 = accr[3] + bf2f((ushort)(cv[1] >> 16));
        uint o0 = (uint)f2bf(r0) | ((uint)f2bf(r1) << 16);
        uint o1 = (uint)f2bf(r2) | ((uint)f2bf(r3) << 16);
        // Reference zero-pads EVERY layer's input at absolute t<0 (tile 0
        // only): force those intermediate values to 0 instead of computed.
        if (t0 + tb + col < 0) { o0 = 0u; o1 = 0u; }
        *(u32x2*)(wbuf + swz(u, g * 8)) = (u32x2){o0, o1};
      }
    };

    for (int gi = 2 * w; gi < ng; gi += 32) {
      body(gi);
      if (gi + 1 < ng) body(gi + 1);
    }

    __syncthreads();
    cur ^= 1;
  }

  outp[b * TT + t0 + tid] = skipL[tid] + mix_b[0];
}

extern "C" void kernel_launch(void* const* d_in, const int* in_sizes, int n_in,
                              void* d_out, int out_size, void* d_ws, size_t ws_size,
                              hipStream_t stream) {
  const float* x     = (const float*)d_in[0];
  const float* in_w  = (const float*)d_in[1];
  const float* in_b  = (const float*)d_in[2];
  const float* hid_w = (const float*)d_in[3];
  const float* hid_b = (const float*)d_in[4];
  const float* res_w = (const float*)d_in[5];
  const float* res_b = (const float*)d_in[6];
  const float* mix_w = (const float*)d_in[7];
  const float* mix_b = (const float*)d_in[8];
  float* outp = (float*)d_out;

  ushort* WA = (ushort*)d_ws;          // 32768 ushorts
  ushort* RA = WA + 32768;             // 8192 ushorts

  wn_prep<<<160, 256, 0, stream>>>(hid_w, res_w, WA, RA);
  wn_fused<<<BB * (TT / TILE), 1024, 0, stream>>>(
      x, in_w, in_b, WA, RA, hid_b, res_b, mix_w, mix_b, outp);
}

// Round 9
// 126.604 us; speedup vs baseline: 3.9689x; 1.0924x over previous
//
#include <hip/hip_runtime.h>
#include <hip/hip_bf16.h>

#define CC 16
#define LL 16
#define TT 32768
#define BB 8
#define TILE 1024                 // output t per block
#define BASEI 1040                // LDS row u = tau + BASEI (tau in [-1040,1024))
#define NSLOT 2064                // rows per buffer
#define BUFB (NSLOT * 32)         // bytes per buffer (66048)

typedef unsigned int uint;
typedef unsigned short ushort;
typedef uint  u32x2 __attribute__((ext_vector_type(2)));
typedef uint  u32x4 __attribute__((ext_vector_type(4)));
typedef float f32x4 __attribute__((ext_vector_type(4)));
typedef short s16x8 __attribute__((ext_vector_type(8)));   // 8 bf16

// floor16 of output-span start s_{i+1} (suffix sums of 2*d), per layer
__device__ const int OST_TAB[LL] = {-1024,-1024,-1008,-992,-960,-896,-768,-512,
                                    -512,-512,-496,-480,-448,-384,-256,0};

__device__ __forceinline__ ushort f2bf(float f) {
  uint u = __float_as_uint(f);
  return (ushort)((u + 0x7FFFu + ((u >> 16) & 1u)) >> 16);   // RNE
}
__device__ __forceinline__ float bf2f(ushort h) {
  return __uint_as_float(((uint)h) << 16);
}
// packed f32x2 -> bf16x2 (v_cvt_pk_bf16_f32 path, RNE)
__device__ __forceinline__ uint cvtpk(float lo, float hi) {
  __hip_bfloat162 h = __float22bfloat162_rn(float2{lo, hi});
  uint r;
  __builtin_memcpy(&r, &h, 4);    // type-pun (bit_cast rejects non-trivial type)
  return r;
}
__device__ __forceinline__ f32x4 mfma16(s16x8 a, s16x8 b, f32x4 c) {
  return __builtin_amdgcn_mfma_f32_16x16x32_bf16(a, b, c, 0, 0, 0);
}
// LDS swizzle base for row u; full addr = base ^ o for o < 32
// ((u<<5) and o are bit-disjoint, X covers bits 4-6 -> XOR-composable)
__device__ __forceinline__ int swzb(int u) {
  return (u << 5) ^ ((u & 28) << 2);
}
__device__ __forceinline__ int swz(int u, int o) {   // prep/stage convenience
  return swzb(u) ^ o;
}

// ---------------- prep: pack weights into MFMA fragment order ----------------
// WA[((l*2+cot)*2+frag)*64 + lane][j]: frag0: k=(g<2?0:1), ci=(g&1)*8+j
//                                     frag1: g<2 -> k=2, ci=g*8+j ; else 0
// RA[l*64+lane][j]: row c=lane&15; g<2 -> c2=g*8+j ; else 0
__global__ __launch_bounds__(256) void wn_prep(
    const float* __restrict__ hw, const float* __restrict__ rw,
    ushort* __restrict__ WA, ushort* __restrict__ RA) {
  int tid = blockIdx.x * 256 + threadIdx.x;      // 40960 total
  if (tid < 32768) {
    int j = tid & 7, lane = (tid >> 3) & 63, frag = (tid >> 9) & 1;
    int cot = (tid >> 10) & 1, l = tid >> 11;
    int co = cot * 16 + (lane & 15), g = lane >> 4;
    float v = 0.f;
    if (frag == 0) {
      int k = (g < 2) ? 0 : 1, ci = (g & 1) * 8 + j;
      v = hw[((l * 32 + co) * 16 + ci) * 3 + k];
    } else if (g < 2) {
      int ci = g * 8 + j;
      v = hw[((l * 32 + co) * 16 + ci) * 3 + 2];
    }
    WA[tid] = f2bf(v);
  } else if (tid < 40960) {
    int r = tid - 32768;
    int j = r & 7, lane = (r >> 3) & 63, l = r >> 9;
    int c = lane & 15, g = lane >> 4;
    float v = 0.f;
    if (g < 2) v = rw[(l * 16 + c) * 16 + (g * 8 + j)];
    RA[r] = f2bf(v);
  }
}

// ---------------- fully fused WaveNet: 16 layers in one launch ----------------
__global__ __launch_bounds__(1024, 4) void wn_fused(
    const float* __restrict__ x, const float* __restrict__ in_w,
    const float* __restrict__ in_b,
    const ushort* __restrict__ WA, const ushort* __restrict__ RA,
    const float* __restrict__ hid_b, const float* __restrict__ res_b,
    const float* __restrict__ mix_w, const float* __restrict__ mix_b,
    float* __restrict__ outp) {
  __shared__ ushort sbuf[2][NSLOT * 16];   // 2 x 66048 B, swizzled [t][16ch] bf16
  __shared__ float skipL[TILE];            // fp32 skip accumulator

  int tid = threadIdx.x;
  int b = blockIdx.x & 7, tile = blockIdx.x >> 3;   // XCD<->batch affinity
  int t0 = tile * TILE;
  char* lds = (char*)sbuf;

  // ---- stage: input 1x1 conv into buf0 over tau in [-1040, 1024) ----
  for (int r = tid; r < NSLOT; r += 1024) {
    int t = t0 + r - BASEI;
    uint pk[8];
    if (t >= 0) {
      float xv = x[b * TT + t];
#pragma unroll
      for (int c = 0; c < 8; ++c) {
        float lo = fmaf(in_w[2 * c], xv, in_b[2 * c]);
        float hi = fmaf(in_w[2 * c + 1], xv, in_b[2 * c + 1]);
        pk[c] = cvtpk(lo, hi);
      }
    } else {
#pragma unroll
      for (int c = 0; c < 8; ++c) pk[c] = 0u;     // causal zero pad (ref: layer-0 input pad)
    }
    *(u32x4*)(lds + swz(r, 0))  = (u32x4){pk[0], pk[1], pk[2], pk[3]};
    *(u32x4*)(lds + swz(r, 16)) = (u32x4){pk[4], pk[5], pk[6], pk[7]};
  }
  skipL[tid] = 0.f;
  __syncthreads();

  int lane = tid & 63, w = tid >> 6;
  int col = lane & 15, g = lane >> 4;
  int cur = 0;

  for (int i = 0; i < LL; ++i) {
    int D = 1 << (i & 7);
    int ost = OST_TAB[i];
    int ng = (TILE - ost) >> 4;
    bool last = (i == LL - 1);

    const s16x8* wa = (const s16x8*)(WA + (size_t)i * 2048);
    s16x8 a00 = wa[lane];
    s16x8 a01 = wa[64 + lane];
    s16x8 a10 = wa[128 + lane];
    s16x8 a11 = wa[192 + lane];
    s16x8 ra  = *(const s16x8*)(RA + (size_t)i * 512 + lane * 8);

    f32x4 b0  = *(const f32x4*)(hid_b + i * 32 + g * 4);
    f32x4 b1  = *(const f32x4*)(hid_b + i * 32 + 16 + g * 4);
    f32x4 mw4 = *(const f32x4*)(mix_w + i * 16 + g * 4);
    f32x4 br  = {0.f, 0.f, 0.f, 0.f};
    if (!last) br = *(const f32x4*)(res_b + i * 16 + g * 4);

    char* rbuf = lds + cur * BUFB;
    char* wbuf = lds + (cur ^ 1) * BUFB;
    int toff0 = (g < 2) ? 2 * D : D;
    int oB = (g & 1) << 4;      // bf0 byte-offset (lane-const)
    int oG = g << 4;            // bf1 byte-offset (g<2 only)
    int oC = g << 3;            // center-tap / write byte-offset

    auto body = [&](int gi) {
      int tb = ost + (gi << 4);
      int u = tb + col + BASEI;
      int sb1 = swzb(u);                 // row-u swizzle base
      int sb0 = swzb(u - toff0);         // tap-row base
      s16x8 bf0 = *(const s16x8*)(rbuf + (sb0 ^ oB));
      s16x8 bf1 = {0, 0, 0, 0, 0, 0, 0, 0};
      if (g < 2) bf1 = *(const s16x8*)(rbuf + (sb1 ^ oG));

      f32x4 acc0 = b0, acc1 = b1;
      acc0 = mfma16(a00, bf0, acc0);
      acc0 = mfma16(a01, bf1, acc0);
      acc1 = mfma16(a10, bf0, acc1);
      acc1 = mfma16(a11, bf1, acc1);

      // gated = tanh(a)*sigmoid(b) = (E-1) / ((E+1)(F+1)), E=e^2a, F=e^-b
      float gg[4];
#pragma unroll
      for (int q = 0; q < 4; ++q) {
        float a = fminf(fmaxf(acc0[q], -15.f), 15.f);
        float bq = fminf(fmaxf(acc1[q], -30.f), 30.f);
        float E = __expf(2.f * a);
        float F = __expf(-bq);
        float r = __builtin_amdgcn_rcpf((E + 1.f) * (F + 1.f));
        gg[q] = (E - 1.f) * r;
      }

      // skip (mix conv folded), only for output-tile region
      float s = gg[0] * mw4[0];
      s = fmaf(gg[1], mw4[1], s);
      s = fmaf(gg[2], mw4[2], s);
      s = fmaf(gg[3], mw4[3], s);
      s += __shfl_xor(s, 16);
      s += __shfl_xor(s, 32);
      if (tb >= 0 && g == 0) skipL[tb + col] += s;

      if (!last) {
        // res-conv B-fragment via cross-lane regroup
        uint u0 = cvtpk(gg[0], gg[1]);
        uint u1 = cvtpk(gg[2], gg[3]);
        int sA = (((g << 1) & 3) << 4) + col;
        int sB = ((((g << 1) | 1) & 3) << 4) + col;
        uint w0 = __shfl(u0, sA), w1 = __shfl(u1, sA);
        uint w2 = __shfl(u0, sB), w3 = __shfl(u1, sB);
        u32x4 gw = {w0, w1, w2, w3};
        if (g >= 2) gw = (u32x4){0, 0, 0, 0};
        s16x8 gb = __builtin_bit_cast(s16x8, gw);

        f32x4 accr = br;
        accr = mfma16(ra, gb, accr);

        u32x2 cv = *(const u32x2*)(rbuf + (sb1 ^ oC));   // center taps
        float r0 = accr[0] + bf2f((ushort)(cv[0] & 0xffff));
        float r1 = accr[1] + bf2f((ushort)(cv[0] >> 16));
        float r2 = accr[2] + bf2f((ushort)(cv[1] & 0xffff));
        float r3 = accr[3] + bf2f((ushort)(cv[1] >> 16));
        uint o0 = cvtpk(r0, r1);
        uint o1 = cvtpk(r2, r3);
        // Reference zero-pads EVERY layer's input at absolute t<0 (tile 0
        // only): force those intermediate values to 0 instead of computed.
        if (t0 + tb + col < 0) { o0 = 0u; o1 = 0u; }
        *(u32x2*)(wbuf + (sb1 ^ oC)) = (u32x2){o0, o1};
      }
    };

    for (int gi = 2 * w; gi < ng; gi += 32) {
      body(gi);
      if (gi + 1 < ng) body(gi + 1);
    }

    __syncthreads();
    cur ^= 1;
  }

  outp[b * TT + t0 + tid] = skipL[tid] + mix_b[0];
}

extern "C" void kernel_launch(void* const* d_in, const int* in_sizes, int n_in,
                              void* d_out, int out_size, void* d_ws, size_t ws_size,
                              hipStream_t stream) {
  const float* x     = (const float*)d_in[0];
  const float* in_w  = (const float*)d_in[1];
  const float* in_b  = (const float*)d_in[2];
  const float* hid_w = (const float*)d_in[3];
  const float* hid_b = (const float*)d_in[4];
  const float* res_w = (const float*)d_in[5];
  const float* res_b = (const float*)d_in[6];
  const float* mix_w = (const float*)d_in[7];
  const float* mix_b = (const float*)d_in[8];
  float* outp = (float*)d_out;

  ushort* WA = (ushort*)d_ws;          // 32768 ushorts
  ushort* RA = WA + 32768;             // 8192 ushorts

  wn_prep<<<160, 256, 0, stream>>>(hid_w, res_w, WA, RA);
  wn_fused<<<BB * (TT / TILE), 1024, 0, stream>>>(
      x, in_w, in_b, WA, RA, hid_b, res_b, mix_w, mix_b, outp);
}

// Round 10
// 113.571 us; speedup vs baseline: 4.4243x; 1.1148x over previous
//
#include <hip/hip_runtime.h>
#include <hip/hip_bf16.h>

#define CC 16
#define LL 16
#define TT 32768
#define BB 8
#define TILE 1024                 // output t per block
#define BASEI 1040                // LDS row u = tau + BASEI (tau in [-1040,1024))
#define NSLOT 2064                // rows per buffer
#define BUFB (NSLOT * 32)         // bytes per buffer (66048)

typedef unsigned int uint;
typedef unsigned short ushort;
typedef uint  u32x2 __attribute__((ext_vector_type(2)));
typedef uint  u32x4 __attribute__((ext_vector_type(4)));
typedef float f32x4 __attribute__((ext_vector_type(4)));
typedef short s16x8 __attribute__((ext_vector_type(8)));   // 8 bf16

// floor16 of output-span start s_{i+1} (suffix sums of 2*d), per layer
__device__ const int OST_TAB[LL] = {-1024,-1024,-1008,-992,-960,-896,-768,-512,
                                    -512,-512,-496,-480,-448,-384,-256,0};

__device__ __forceinline__ ushort f2bf(float f) {
  uint u = __float_as_uint(f);
  return (ushort)((u + 0x7FFFu + ((u >> 16) & 1u)) >> 16);   // RNE
}
// packed f32x2 -> bf16x2 (v_cvt_pk_bf16_f32 path, RNE)
__device__ __forceinline__ uint cvtpk(float lo, float hi) {
  __hip_bfloat162 h = __float22bfloat162_rn(float2{lo, hi});
  uint r;
  __builtin_memcpy(&r, &h, 4);    // type-pun (bit_cast rejects non-trivial type)
  return r;
}
__device__ __forceinline__ f32x4 mfma16(s16x8 a, s16x8 b, f32x4 c) {
  return __builtin_amdgcn_mfma_f32_16x16x32_bf16(a, b, c, 0, 0, 0);
}
// LDS swizzle base for row u; full addr = base ^ o for o < 32.
// Key property: swzb(u + 512) == swzb(u) + 16384 (bits are carry-disjoint),
// so bases strength-reduce across the gi += 32 loop.
__device__ __forceinline__ int swzb(int u) {
  return (u << 5) ^ ((u & 28) << 2);
}
__device__ __forceinline__ int swz(int u, int o) {   // staging convenience
  return swzb(u) ^ o;
}

// ---------------- prep: pack weights into MFMA fragment order ----------------
// WA[((l*2+cot)*2+frag)*64 + lane][j]: frag0: k=(g<2?0:1), ci=(g&1)*8+j
//                                     frag1: g<2 -> k=2, ci=g*8+j ; else 0
// RA[l*64+lane][j]: row c=lane&15; g<2 -> res weight c2=g*8+j
//                   g>=2 -> IDENTITY delta(c, (g-2)*8+j)  (residual-in-MFMA)
__global__ __launch_bounds__(256) void wn_prep(
    const float* __restrict__ hw, const float* __restrict__ rw,
    ushort* __restrict__ WA, ushort* __restrict__ RA) {
  int tid = blockIdx.x * 256 + threadIdx.x;      // 40960 total
  if (tid < 32768) {
    int j = tid & 7, lane = (tid >> 3) & 63, frag = (tid >> 9) & 1;
    int cot = (tid >> 10) & 1, l = tid >> 11;
    int co = cot * 16 + (lane & 15), g = lane >> 4;
    float v = 0.f;
    if (frag == 0) {
      int k = (g < 2) ? 0 : 1, ci = (g & 1) * 8 + j;
      v = hw[((l * 32 + co) * 16 + ci) * 3 + k];
    } else if (g < 2) {
      int ci = g * 8 + j;
      v = hw[((l * 32 + co) * 16 + ci) * 3 + 2];
    }
    WA[tid] = f2bf(v);
  } else if (tid < 40960) {
    int r = tid - 32768;
    int j = r & 7, lane = (r >> 3) & 63, l = r >> 9;
    int c = lane & 15, g = lane >> 4;
    float v;
    if (g < 2) v = rw[(l * 16 + c) * 16 + (g * 8 + j)];
    else       v = (c == (g - 2) * 8 + j) ? 1.f : 0.f;   // identity: +x_center
    RA[r] = f2bf(v);
  }
}

// ---------------- fully fused WaveNet: 16 layers in one launch ----------------
__global__ __launch_bounds__(1024, 4) void wn_fused(
    const float* __restrict__ x, const float* __restrict__ in_w,
    const float* __restrict__ in_b,
    const ushort* __restrict__ WA, const ushort* __restrict__ RA,
    const float* __restrict__ hid_b, const float* __restrict__ res_b,
    const float* __restrict__ mix_w, const float* __restrict__ mix_b,
    float* __restrict__ outp) {
  __shared__ ushort sbuf[2][NSLOT * 16];   // 2 x 66048 B, swizzled [t][16ch] bf16
  __shared__ float skipH0[TILE];           // skip partial (gates 0-7)
  __shared__ float skipH1[TILE];           // skip partial (gates 8-15)

  int tid = threadIdx.x;
  int b = blockIdx.x & 7, tile = blockIdx.x >> 3;   // XCD<->batch affinity
  int t0 = tile * TILE;
  char* lds = (char*)sbuf;

  // ---- stage: input 1x1 conv into buf0 over tau in [-1040, 1024) ----
  for (int r = tid; r < NSLOT; r += 1024) {
    int t = t0 + r - BASEI;
    uint pk[8];
    if (t >= 0) {
      float xv = x[b * TT + t];
#pragma unroll
      for (int c = 0; c < 8; ++c) {
        float lo = fmaf(in_w[2 * c], xv, in_b[2 * c]);
        float hi = fmaf(in_w[2 * c + 1], xv, in_b[2 * c + 1]);
        pk[c] = cvtpk(lo, hi);
      }
    } else {
#pragma unroll
      for (int c = 0; c < 8; ++c) pk[c] = 0u;     // causal zero pad
    }
    *(u32x4*)(lds + swz(r, 0))  = (u32x4){pk[0], pk[1], pk[2], pk[3]};
    *(u32x4*)(lds + swz(r, 16)) = (u32x4){pk[4], pk[5], pk[6], pk[7]};
  }
  skipH0[tid] = 0.f;
  skipH1[tid] = 0.f;
  __syncthreads();

  int lane = tid & 63, w = tid >> 6;
  int col = lane & 15, g = lane >> 4;
  int gi0 = 2 * w;
  // cross-lane regroup source lanes (loop-invariant)
  int sA = (((g << 1) & 3) << 4) + col;
  int sB = ((((g << 1) | 1) & 3) << 4) + col;
  int oH = (g & 1) << 4;      // B-frag byte offset (both taps AND res V)
  int oC = g << 3;            // residual-write byte offset
  int cur = 0;

  for (int i = 0; i < LL; ++i) {
    int D = 1 << (i & 7);
    int ost = OST_TAB[i];
    int ng = (TILE - ost) >> 4;
    bool last = (i == LL - 1);

    const s16x8* wa = (const s16x8*)(WA + (size_t)i * 2048);
    s16x8 a00 = wa[lane];
    s16x8 a01 = wa[64 + lane];
    s16x8 a10 = wa[128 + lane];
    s16x8 a11 = wa[192 + lane];
    s16x8 ra  = *(const s16x8*)(RA + (size_t)i * 512 + lane * 8);

    f32x4 b0  = *(const f32x4*)(hid_b + i * 32 + g * 4);
    f32x4 b1  = *(const f32x4*)(hid_b + i * 32 + 16 + g * 4);
    f32x4 mw4 = *(const f32x4*)(mix_w + i * 16 + g * 4);
    f32x4 br  = {0.f, 0.f, 0.f, 0.f};
    if (!last) br = *(const f32x4*)(res_b + i * 16 + g * 4);

    int rb = cur * BUFB;
    int wdelta = cur ? -BUFB : BUFB;
    int toff0 = (g < 2) ? 2 * D : D;

    // strength-reduced swizzle bases (+= 16384 per gi += 32)
    int u0r = ost + (gi0 << 4) + col + BASEI;
    int A1 = rb + swzb(u0r);
    int A0 = rb + swzb(u0r - toff0);
    int B1 = rb + swzb(u0r + 16);
    int B0 = rb + swzb(u0r + 16 - toff0);
    int tr  = ost + (gi0 << 4) + col;      // tile-relative t
    int tab = t0 + tr;                     // absolute t (guard, tile 0 only)

    auto body = [&](int a0, int a1, int trel, int tabs) {
      s16x8 bf0 = *(const s16x8*)(lds + (a0 ^ oH));   // taps k=0 / k=1
      s16x8 V   = *(const s16x8*)(lds + (a1 ^ oH));   // center taps (k=2 + res)

      f32x4 acc0 = mfma16(a00, bf0, b0);
      acc0 = mfma16(a01, V, acc0);        // g>=2 K-slots of a01 are 0
      f32x4 acc1 = mfma16(a10, bf0, b1);
      acc1 = mfma16(a11, V, acc1);

      // gated = tanh(a)*sigmoid(b) = (E-1)/((E+1)(F+1)), E=e^2a, F=e^-b
      float gg[4];
#pragma unroll
      for (int q = 0; q < 4; ++q) {
        float a = fminf(fmaxf(acc0[q], -15.f), 15.f);
        float bq = fminf(fmaxf(acc1[q], -30.f), 30.f);
        float E = __expf(2.f * a);
        float F = __expf(-bq);
        float r = __builtin_amdgcn_rcpf((E + 1.f) * (F + 1.f));
        gg[q] = (E - 1.f) * r;
      }

      // skip (mix conv folded): one xor16; g=0 and g=2 write the two halves
      float s = gg[0] * mw4[0];
      s = fmaf(gg[1], mw4[1], s);
      s = fmaf(gg[2], mw4[2], s);
      s = fmaf(gg[3], mw4[3], s);
      s += __shfl_xor(s, 16);
      if (trel >= 0 && (g & 1) == 0) {
        float* sp = (g & 2) ? skipH1 : skipH0;
        sp[trel] += s;
      }

      if (!last) {
        // res-conv B-frag: g<2 = regrouped gates; g>=2 = center taps (identity
        // rows in RA add the residual inside the same MFMA)
        uint p0 = cvtpk(gg[0], gg[1]);
        uint p1 = cvtpk(gg[2], gg[3]);
        uint w0 = __shfl(p0, sA), w1 = __shfl(p1, sA);
        uint w2 = __shfl(p0, sB), w3 = __shfl(p1, sB);
        s16x8 gb;
        if (g < 2) {
          u32x4 gw = {w0, w1, w2, w3};
          gb = __builtin_bit_cast(s16x8, gw);
        } else {
          gb = V;
        }
        f32x4 accr = mfma16(ra, gb, br);

        uint o0 = cvtpk(accr[0], accr[1]);
        uint o1 = cvtpk(accr[2], accr[3]);
        // Reference zero-pads EVERY layer's input at absolute t<0 (tile 0)
        if (tabs < 0) { o0 = 0u; o1 = 0u; }
        *(u32x2*)(lds + ((a1 ^ oC) + wdelta)) = (u32x2){o0, o1};
      }
    };

    for (int gi = gi0; gi < ng; gi += 32) {
      body(A0, A1, tr, tab);
      if (gi + 1 < ng) body(B0, B1, tr + 16, tab + 16);
      A0 += 16384; A1 += 16384; B0 += 16384; B1 += 16384;
      tr += 512; tab += 512;
    }

    __syncthreads();
    cur ^= 1;
  }

  outp[b * TT + t0 + tid] = skipH0[tid] + skipH1[tid] + mix_b[0];
}

extern "C" void kernel_launch(void* const* d_in, const int* in_sizes, int n_in,
                              void* d_out, int out_size, void* d_ws, size_t ws_size,
                              hipStream_t stream) {
  const float* x     = (const float*)d_in[0];
  const float* in_w  = (const float*)d_in[1];
  const float* in_b  = (const float*)d_in[2];
  const float* hid_w = (const float*)d_in[3];
  const float* hid_b = (const float*)d_in[4];
  const float* res_w = (const float*)d_in[5];
  const float* res_b = (const float*)d_in[6];
  const float* mix_w = (const float*)d_in[7];
  const float* mix_b = (const float*)d_in[8];
  float* outp = (float*)d_out;

  ushort* WA = (ushort*)d_ws;          // 32768 ushorts
  ushort* RA = WA + 32768;             // 8192 ushorts

  wn_prep<<<160, 256, 0, stream>>>(hid_w, res_w, WA, RA);
  wn_fused<<<BB * (TT / TILE), 1024, 0, stream>>>(
      x, in_w, in_b, WA, RA, hid_b, res_b, mix_w, mix_b, outp);
}

// Round 11
// 103.129 us; speedup vs baseline: 4.8723x; 1.1012x over previous
//
#include <hip/hip_runtime.h>
#include <hip/hip_bf16.h>

#define LL 16
#define TT 32768
#define BB 8
#define TILE 1024                 // output t per block
#define BASEI 1040                // LDS row u = tau + BASEI
#define NSLOT 2064                // rows per buffer
#define BUFB (NSLOT * 32)         // bytes per buffer (66048)

typedef unsigned int uint;
typedef unsigned short ushort;
typedef uint  u32x2 __attribute__((ext_vector_type(2)));
typedef uint  u32x4 __attribute__((ext_vector_type(4)));
typedef float f32x4 __attribute__((ext_vector_type(4)));
typedef float f32x16 __attribute__((ext_vector_type(16)));
typedef short s16x8 __attribute__((ext_vector_type(8)));   // 8 bf16

// floor32 of the old OST table; forward-induction verified: v[16]=0,
// all gated-validity v[i]+2d[i] <= 0, min read row u=8 >= 0.
__device__ const int OST32_TAB[LL] = {-1024,-1024,-1024,-992,-960,-896,-768,-512,
                                      -512,-512,-512,-480,-448,-384,-256,0};

__device__ __forceinline__ ushort f2bf(float f) {
  uint u = __float_as_uint(f);
  return (ushort)((u + 0x7FFFu + ((u >> 16) & 1u)) >> 16);   // RNE
}
__device__ __forceinline__ uint cvtpk(float lo, float hi) {
  __hip_bfloat162 h = __float22bfloat162_rn(float2{lo, hi});
  uint r;
  __builtin_memcpy(&r, &h, 4);
  return r;
}
__device__ __forceinline__ f32x16 mfma32(s16x8 a, s16x8 b, f32x16 c) {
  return __builtin_amdgcn_mfma_f32_32x32x16_bf16(a, b, c, 0, 0, 0);
}
// swizzle: addr = swzb(u) ^ o (o < 32); swzb(u+512) = swzb(u)+16384,
// swzb(u+32) = swzb(u)+1024 (carry-disjoint).
__device__ __forceinline__ int swzb(int u) {
  return (u << 5) ^ ((u & 28) << 2);
}
__device__ __forceinline__ int swz(int u, int o) { return swzb(u) ^ o; }

// ---------------- prep: pack weights into 32x32x16 fragment order -----------
// WA32[l][kt][lane][j]: A row co=lane&31, K-slot s=(lane>>5)*8+j = ci, tap kt
// RA[l][0][lane][j]: rows 0-15 = res weight R[row][s], rows 16-31 = 0
// RA[l][1][lane][j]: rows 0-15 = identity delta(row,s), rows 16-31 = 0
__global__ __launch_bounds__(256) void wn_prep(
    const float* __restrict__ hw, const float* __restrict__ rw,
    ushort* __restrict__ WA, ushort* __restrict__ RA) {
  int tid = blockIdx.x * 256 + threadIdx.x;      // 40960 total
  if (tid < 24576) {
    int j = tid & 7, lane = (tid >> 3) & 63;
    int rem = tid >> 9;                          // l*3 + kt
    int kt = rem % 3, l = rem / 3;
    int row = lane & 31, s = (lane >> 5) * 8 + j;
    WA[tid] = f2bf(hw[((l * 32 + row) * 16 + s) * 3 + kt]);
  } else if (tid < 40960) {
    int r = tid - 24576;
    int j = r & 7, lane = (r >> 3) & 63;
    int rem = r >> 9;                            // l*2 + which
    int which = rem & 1, l = rem >> 1;
    int row = lane & 31, s = (lane >> 5) * 8 + j;
    float v = 0.f;
    if (row < 16) {
      if (which == 0) v = rw[(l * 16 + row) * 16 + s];
      else            v = (row == s) ? 1.f : 0.f;
    }
    RA[r] = f2bf(v);
  }
}

// ---------------- fully fused WaveNet, 32x32 MFMA bodies ---------------------
__global__ __launch_bounds__(1024, 4) void wn_fused(
    const float* __restrict__ x, const float* __restrict__ in_w,
    const float* __restrict__ in_b,
    const ushort* __restrict__ WA, const ushort* __restrict__ RA,
    const float* __restrict__ hid_b, const float* __restrict__ res_b,
    const float* __restrict__ mix_w, const float* __restrict__ mix_b,
    float* __restrict__ outp) {
  __shared__ ushort sbuf[2][NSLOT * 16];   // 2 x 66048 B, swizzled [t][16ch] bf16
  __shared__ float skipH0[TILE];           // skip partials (per-lane hi halves)
  __shared__ float skipH1[TILE];

  int tid = threadIdx.x;
  int b = blockIdx.x & 7, tile = blockIdx.x >> 3;   // XCD<->batch affinity
  int t0 = tile * TILE;
  char* lds = (char*)sbuf;

  // ---- stage: input 1x1 conv into buf0 over tau in [-1040, 1024) ----
  for (int r = tid; r < NSLOT; r += 1024) {
    int t = t0 + r - BASEI;
    uint pk[8];
    if (t >= 0) {
      float xv = x[b * TT + t];
#pragma unroll
      for (int c = 0; c < 8; ++c) {
        float lo = fmaf(in_w[2 * c], xv, in_b[2 * c]);
        float hi = fmaf(in_w[2 * c + 1], xv, in_b[2 * c + 1]);
        pk[c] = cvtpk(lo, hi);
      }
    } else {
#pragma unroll
      for (int c = 0; c < 8; ++c) pk[c] = 0u;     // causal zero pad
    }
    *(u32x4*)(lds + swz(r, 0))  = (u32x4){pk[0], pk[1], pk[2], pk[3]};
    *(u32x4*)(lds + swz(r, 16)) = (u32x4){pk[4], pk[5], pk[6], pk[7]};
  }
  skipH0[tid] = 0.f;
  skipH1[tid] = 0.f;
  __syncthreads();

  int lane = tid & 63, w = tid >> 6;
  int col32 = lane & 31, hi = lane >> 5;
  int lanex = lane ^ 32;
  int oG  = hi << 4;          // B-frag load byte offset
  int oW0 = hi << 3;          // res write: channels 4hi..4hi+3
  int oW1 = 16 + (hi << 3);   // res write: channels 8+4hi..
  int cur = 0;

  for (int i = 0; i < LL; ++i) {
    int D = 1 << (i & 7);
    int ost = OST32_TAB[i];
    int ng32 = (TILE - ost) >> 5;
    bool last = (i == LL - 1);

    const s16x8* wa = (const s16x8*)(WA + (size_t)i * 1536);
    s16x8 wa0 = wa[lane];            // tap k=0
    s16x8 wa1 = wa[64 + lane];       // tap k=1
    s16x8 wa2 = wa[128 + lane];      // tap k=2
    const s16x8* rp = (const s16x8*)(RA + (size_t)i * 1024);
    s16x8 ra1 = rp[lane];            // res weights
    s16x8 ra2 = rp[64 + lane];       // identity (residual add)

    // bias / mix fragments (C/D rows for this lane's hi)
    f32x4 hb0 = *(const f32x4*)(hid_b + i * 32 + 4 * hi);
    f32x4 hb1 = *(const f32x4*)(hid_b + i * 32 + 8 + 4 * hi);
    f32x4 hb2 = *(const f32x4*)(hid_b + i * 32 + 16 + 4 * hi);
    f32x4 hb3 = *(const f32x4*)(hid_b + i * 32 + 24 + 4 * hi);
    f32x16 bini;
#pragma unroll
    for (int q = 0; q < 4; ++q) {
      bini[q] = hb0[q]; bini[4 + q] = hb1[q];
      bini[8 + q] = hb2[q]; bini[12 + q] = hb3[q];
    }
    f32x4 mwA = *(const f32x4*)(mix_w + i * 16 + 4 * hi);
    f32x4 mwB = *(const f32x4*)(mix_w + i * 16 + 8 + 4 * hi);
    f32x16 rini;
    if (!last) {
      f32x4 rb0 = *(const f32x4*)(res_b + i * 16 + 4 * hi);
      f32x4 rb1 = *(const f32x4*)(res_b + i * 16 + 8 + 4 * hi);
#pragma unroll
      for (int q = 0; q < 4; ++q) {
        rini[q] = rb0[q]; rini[4 + q] = rb1[q];
        rini[8 + q] = 0.f; rini[12 + q] = 0.f;
      }
    }

    int rb = cur * BUFB;
    int wdelta = cur ? -BUFB : BUFB;
    float* sp = hi ? skipH1 : skipH0;

    int u0 = ost + w * 32 + col32 + BASEI;
    int A2 = rb + swzb(u0);
    int A1 = rb + swzb(u0 - D);
    int A0 = rb + swzb(u0 - 2 * D);
    int trel = ost + w * 32 + col32;
    int tabs = t0 + trel;

    for (int gi = w; gi < ng32; gi += 16) {
      s16x8 q0 = *(const s16x8*)(lds + (A0 ^ oG));
      s16x8 q1 = *(const s16x8*)(lds + (A1 ^ oG));
      s16x8 q2 = *(const s16x8*)(lds + (A2 ^ oG));

      f32x16 acc = bini;
      acc = mfma32(wa0, q0, acc);
      acc = mfma32(wa1, q1, acc);
      acc = mfma32(wa2, q2, acc);

      // gated = tanh(a)*sigmoid(b) = (E-1)/((E+1)(F+1)); pairs acc[r],acc[r+8]
      float gg[8];
#pragma unroll
      for (int r = 0; r < 8; ++r) {
        float a  = fminf(fmaxf(acc[r], -15.f), 15.f);
        float bq = fminf(fmaxf(acc[r + 8], -30.f), 30.f);
        float E = __expf(2.f * a);
        float F = __expf(-bq);
        float rr = __builtin_amdgcn_rcpf((E + 1.f) * (F + 1.f));
        gg[r] = (E - 1.f) * rr;
      }

      // skip (mix folded): each lane owns half the channels of its t -> no shfl
      float s = gg[0] * mwA[0];
      s = fmaf(gg[1], mwA[1], s);
      s = fmaf(gg[2], mwA[2], s);
      s = fmaf(gg[3], mwA[3], s);
      s = fmaf(gg[4], mwB[0], s);
      s = fmaf(gg[5], mwB[1], s);
      s = fmaf(gg[6], mwB[2], s);
      s = fmaf(gg[7], mwB[3], s);
      if (trel >= 0) sp[trel] += s;

      if (!last) {
        // res B-frag: own chpairs + partner's via z-select + 2 shfl
        uint O0 = cvtpk(gg[0], gg[1]);   // chpair 4hi
        uint O1 = cvtpk(gg[2], gg[3]);   // chpair 4hi+2
        uint O2 = cvtpk(gg[4], gg[5]);   // chpair 8+4hi
        uint O3 = cvtpk(gg[6], gg[7]);   // chpair 8+4hi+2
        uint z0 = hi ? O0 : O2;
        uint z1 = hi ? O1 : O3;
        uint r0 = (uint)__shfl((int)z0, lanex);
        uint r1 = (uint)__shfl((int)z1, lanex);
        uint s0 = hi ? r0 : O0;
        uint s1 = hi ? r1 : O1;
        uint s2 = hi ? O2 : r0;
        uint s3 = hi ? O3 : r1;
        u32x4 gw = {s0, s1, s2, s3};
        s16x8 gb = __builtin_bit_cast(s16x8, gw);

        f32x16 accr = rini;
        accr = mfma32(ra1, gb, accr);    // R @ gates + res_b
        accr = mfma32(ra2, q2, accr);    // + identity @ center taps (residual)

        uint o0 = cvtpk(accr[0], accr[1]);
        uint o1 = cvtpk(accr[2], accr[3]);
        uint o2 = cvtpk(accr[4], accr[5]);
        uint o3 = cvtpk(accr[6], accr[7]);
        if (tabs < 0) { o0 = 0u; o1 = 0u; o2 = 0u; o3 = 0u; }  // ref zero-pad
        *(u32x2*)(lds + ((A2 + wdelta) ^ oW0)) = (u32x2){o0, o1};
        *(u32x2*)(lds + ((A2 + wdelta) ^ oW1)) = (u32x2){o2, o3};
      }

      A0 += 16384; A1 += 16384; A2 += 16384;
      trel += 512; tabs += 512;
    }

    __syncthreads();
    cur ^= 1;
  }

  outp[b * TT + t0 + tid] = skipH0[tid] + skipH1[tid] + mix_b[0];
}

extern "C" void kernel_launch(void* const* d_in, const int* in_sizes, int n_in,
                              void* d_out, int out_size, void* d_ws, size_t ws_size,
                              hipStream_t stream) {
  const float* x     = (const float*)d_in[0];
  const float* in_w  = (const float*)d_in[1];
  const float* in_b  = (const float*)d_in[2];
  const float* hid_w = (const float*)d_in[3];
  const float* hid_b = (const float*)d_in[4];
  const float* res_w = (const float*)d_in[5];
  const float* res_b = (const float*)d_in[6];
  const float* mix_w = (const float*)d_in[7];
  const float* mix_b = (const float*)d_in[8];
  float* outp = (float*)d_out;

  ushort* WA = (ushort*)d_ws;          // 24576 ushorts
  ushort* RA = WA + 24576;             // 16384 ushorts

  wn_prep<<<160, 256, 0, stream>>>(hid_w, res_w, WA, RA);
  wn_fused<<<BB * (TT / TILE), 1024, 0, stream>>>(
      x, in_w, in_b, WA, RA, hid_b, res_b, mix_w, mix_b, outp);
}

// Round 12
// 100.981 us; speedup vs baseline: 4.9760x; 1.0213x over previous
//
#include <hip/hip_runtime.h>
#include <hip/hip_bf16.h>

#define LL 16
#define TT 32768
#define BB 8
#define TILE 1024                 // output t per block
#define BASEI 1152                // LDS row u = tau + BASEI (covers 512-rounded halo)
#define NSLOT 2176                // rows per buffer
#define BUFB (NSLOT * 32)         // bytes per buffer (69632)

typedef unsigned int uint;
typedef unsigned short ushort;
typedef uint  u32x2 __attribute__((ext_vector_type(2)));
typedef uint  u32x4 __attribute__((ext_vector_type(4)));
typedef float f32x4 __attribute__((ext_vector_type(4)));
typedef float f32x16 __attribute__((ext_vector_type(16)));
typedef short s16x8 __attribute__((ext_vector_type(8)));   // 8 bf16

#define S_T 2.885390081777927f     // 2*log2(e)  (tanh rows prescale)
#define S_S -1.4426950408889634f   // -log2(e)   (sigmoid rows prescale)

__device__ __forceinline__ ushort f2bf(float f) {
  uint u = __float_as_uint(f);
  return (ushort)((u + 0x7FFFu + ((u >> 16) & 1u)) >> 16);   // RNE
}
__device__ __forceinline__ uint cvtpk(float lo, float hi) {
  __hip_bfloat162 h = __float22bfloat162_rn(float2{lo, hi});
  uint r;
  __builtin_memcpy(&r, &h, 4);
  return r;
}
__device__ __forceinline__ float fexp2(float x) {
#if __has_builtin(__builtin_amdgcn_exp2f)
  return __builtin_amdgcn_exp2f(x);
#else
  return exp2f(x);
#endif
}
__device__ __forceinline__ f32x16 mfma32(s16x8 a, s16x8 b, f32x16 c) {
  return __builtin_amdgcn_mfma_f32_32x32x16_bf16(a, b, c, 0, 0, 0);
}
// swizzle: addr = swzb(u) ^ o (o < 32); swzb(u+512) = swzb(u)+16384.
__device__ __forceinline__ int swzb(int u) {
  return (u << 5) ^ ((u & 28) << 2);
}
__device__ __forceinline__ int swz(int u, int o) { return swzb(u) ^ o; }

// ---------------- prep: pack weights into 32x32x16 fragment order -----------
// WA[l][kt][lane][j]: A row co=lane&31, K-slot s=(lane>>5)*8+j = ci, tap kt.
// Rows <16 prescaled by 2*log2(e) (tanh), rows >=16 by -log2(e) (sigmoid).
// RA[l][0][lane][j]: rows 0-15 = res weight R[row][s], rows 16-31 = 0
// RA[l][1][lane][j]: rows 0-15 = identity delta(row,s), rows 16-31 = 0
__global__ __launch_bounds__(256) void wn_prep(
    const float* __restrict__ hw, const float* __restrict__ rw,
    ushort* __restrict__ WA, ushort* __restrict__ RA) {
  int tid = blockIdx.x * 256 + threadIdx.x;      // 40960 total
  if (tid < 24576) {
    int j = tid & 7, lane = (tid >> 3) & 63;
    int rem = tid >> 9;                          // l*3 + kt
    int kt = rem % 3, l = rem / 3;
    int row = lane & 31, s = (lane >> 5) * 8 + j;
    float scale = (row < 16) ? S_T : S_S;
    WA[tid] = f2bf(hw[((l * 32 + row) * 16 + s) * 3 + kt] * scale);
  } else if (tid < 40960) {
    int r = tid - 24576;
    int j = r & 7, lane = (r >> 3) & 63;
    int rem = r >> 9;                            // l*2 + which
    int which = rem & 1, l = rem >> 1;
    int row = lane & 31, s = (lane >> 5) * 8 + j;
    float v = 0.f;
    if (row < 16) {
      if (which == 0) v = rw[(l * 16 + row) * 16 + s];
      else            v = (row == s) ? 1.f : 0.f;
    }
    RA[r] = f2bf(v);
  }
}

// ---------------- fully fused WaveNet, 32x32 MFMA bodies ---------------------
__global__ __launch_bounds__(1024, 4) void wn_fused(
    const float* __restrict__ x, const float* __restrict__ in_w,
    const float* __restrict__ in_b,
    const ushort* __restrict__ WA, const ushort* __restrict__ RA,
    const float* __restrict__ hid_b, const float* __restrict__ res_b,
    const float* __restrict__ mix_w, const float* __restrict__ mix_b,
    float* __restrict__ outp) {
  __shared__ ushort sbuf[2][NSLOT * 16];   // 2 x 69632 B, swizzled [t][16ch] bf16

  int tid = threadIdx.x;
  int b = blockIdx.x & 7, tile = blockIdx.x >> 3;   // XCD<->batch affinity
  int t0 = tile * TILE;
  char* lds = (char*)sbuf;

  // ---- stage: input 1x1 conv into buf0 over tau in [-1152, 1024) ----
  for (int r = tid; r < NSLOT; r += 1024) {
    int t = t0 + r - BASEI;
    uint pk[8];
    if (t >= 0) {
      float xv = x[b * TT + t];
#pragma unroll
      for (int c = 0; c < 8; ++c) {
        float lo = fmaf(in_w[2 * c], xv, in_b[2 * c]);
        float hi = fmaf(in_w[2 * c + 1], xv, in_b[2 * c + 1]);
        pk[c] = cvtpk(lo, hi);
      }
    } else {
#pragma unroll
      for (int c = 0; c < 8; ++c) pk[c] = 0u;     // causal zero pad
    }
    *(u32x4*)(lds + swz(r, 0))  = (u32x4){pk[0], pk[1], pk[2], pk[3]};
    *(u32x4*)(lds + swz(r, 16)) = (u32x4){pk[4], pk[5], pk[6], pk[7]};
  }
  __syncthreads();

  int lane = tid & 63, w = tid >> 6;
  int col32 = lane & 31, hi = lane >> 5;
  int lanex = lane ^ 32;
  int oG  = hi << 4;          // B-frag load byte offset
  int oW0 = hi << 3;          // res write: channels 4hi..4hi+3
  int oW1 = 16 + (hi << 3);   // res write: channels 8+4hi..
  int X = w * 32 + col32;     // this lane's output t (chunk A); B = X+512
  float skipA = 0.f, skipB = 0.f;
  int cur = 0;

  for (int i = 0; i < LL; ++i) {
    int D = 1 << (i & 7);
    int ost   = (i < 7) ? -1024 : ((i < 15) ? -512 : 0);   // 512-rounded spans
    int halos = (i < 7) ? 2 : ((i < 15) ? 1 : 0);
    bool last = (i == LL - 1);

    const s16x8* wa = (const s16x8*)(WA + (size_t)i * 1536);
    s16x8 wa0 = wa[lane];            // tap k=0 (prescaled)
    s16x8 wa1 = wa[64 + lane];       // tap k=1
    s16x8 wa2 = wa[128 + lane];      // tap k=2
    const s16x8* rp = (const s16x8*)(RA + (size_t)i * 1024);
    s16x8 ra1 = rp[lane];            // res weights
    s16x8 ra2 = rp[64 + lane];       // identity (residual add)

    // bias fragments, prescaled to exp2 domain
    f32x4 hb0 = *(const f32x4*)(hid_b + i * 32 + 4 * hi);
    f32x4 hb1 = *(const f32x4*)(hid_b + i * 32 + 8 + 4 * hi);
    f32x4 hb2 = *(const f32x4*)(hid_b + i * 32 + 16 + 4 * hi);
    f32x4 hb3 = *(const f32x4*)(hid_b + i * 32 + 24 + 4 * hi);
    f32x16 bini;
#pragma unroll
    for (int q = 0; q < 4; ++q) {
      bini[q] = hb0[q] * S_T; bini[4 + q] = hb1[q] * S_T;
      bini[8 + q] = hb2[q] * S_S; bini[12 + q] = hb3[q] * S_S;
    }
    f32x4 mwA = *(const f32x4*)(mix_w + i * 16 + 4 * hi);
    f32x4 mwB = *(const f32x4*)(mix_w + i * 16 + 8 + 4 * hi);
    f32x16 rini;
    if (!last) {
      f32x4 rb0 = *(const f32x4*)(res_b + i * 16 + 4 * hi);
      f32x4 rb1 = *(const f32x4*)(res_b + i * 16 + 8 + 4 * hi);
#pragma unroll
      for (int q = 0; q < 4; ++q) {
        rini[q] = rb0[q]; rini[4 + q] = rb1[q];
        rini[8 + q] = 0.f; rini[12 + q] = 0.f;
      }
    }

    int rb = cur * BUFB;
    int wdelta = cur ? -BUFB : BUFB;
    int u0 = ost + X + BASEI;
    int A2 = rb + swzb(u0);
    int A1 = rb + swzb(u0 - D);
    int A0 = rb + swzb(u0 - 2 * D);
    int tabs = t0 + ost + X;

    auto body = [&](int mode) {   // 0 = halo, 1 = output A, 2 = output B
      s16x8 q0 = *(const s16x8*)(lds + (A0 ^ oG));
      s16x8 q1 = *(const s16x8*)(lds + (A1 ^ oG));
      s16x8 q2 = *(const s16x8*)(lds + (A2 ^ oG));

      f32x16 acc = bini;
      acc = mfma32(wa0, q0, acc);
      acc = mfma32(wa1, q1, acc);
      acc = mfma32(wa2, q2, acc);

      // gated = (E-1)/((E+1)(F+1)), E=exp2(acc_t), F=exp2(acc_s) (prescaled)
      float gg[8];
#pragma unroll
      for (int r = 0; r < 8; ++r) {
        float E = fexp2(fminf(acc[r], 63.f));
        float F = fexp2(fminf(acc[r + 8], 63.f));
        gg[r] = (E - 1.f) * __builtin_amdgcn_rcpf((E + 1.f) * (F + 1.f));
      }

      if (mode) {   // skip (mix folded) only in output bodies, reg accumulate
        float s = gg[0] * mwA[0];
        s = fmaf(gg[1], mwA[1], s);
        s = fmaf(gg[2], mwA[2], s);
        s = fmaf(gg[3], mwA[3], s);
        s = fmaf(gg[4], mwB[0], s);
        s = fmaf(gg[5], mwB[1], s);
        s = fmaf(gg[6], mwB[2], s);
        s = fmaf(gg[7], mwB[3], s);
        if (mode == 1) skipA += s; else skipB += s;
      }

      if (!last) {
        // res B-frag: own chpairs + partner's via z-select + 2 shfl
        uint O0 = cvtpk(gg[0], gg[1]);
        uint O1 = cvtpk(gg[2], gg[3]);
        uint O2 = cvtpk(gg[4], gg[5]);
        uint O3 = cvtpk(gg[6], gg[7]);
        uint z0 = hi ? O0 : O2;
        uint z1 = hi ? O1 : O3;
        uint r0 = (uint)__shfl((int)z0, lanex);
        uint r1 = (uint)__shfl((int)z1, lanex);
        uint s0 = hi ? r0 : O0;
        uint s1 = hi ? r1 : O1;
        uint s2 = hi ? O2 : r0;
        uint s3 = hi ? O3 : r1;
        u32x4 gw = {s0, s1, s2, s3};
        s16x8 gb = __builtin_bit_cast(s16x8, gw);

        f32x16 accr = rini;
        accr = mfma32(ra1, gb, accr);    // R @ gates + res_b
        accr = mfma32(ra2, q2, accr);    // + identity @ center taps (residual)

        uint o0 = cvtpk(accr[0], accr[1]);
        uint o1 = cvtpk(accr[2], accr[3]);
        uint o2 = cvtpk(accr[4], accr[5]);
        uint o3 = cvtpk(accr[6], accr[7]);
        if (mode == 0 && tabs < 0) { o0 = 0u; o1 = 0u; o2 = 0u; o3 = 0u; }
        *(u32x2*)(lds + ((A2 + wdelta) ^ oW0)) = (u32x2){o0, o1};
        *(u32x2*)(lds + ((A2 + wdelta) ^ oW1)) = (u32x2){o2, o3};
      }

      A0 += 16384; A1 += 16384; A2 += 16384;
      tabs += 512;
    };

    for (int h = 0; h < halos; ++h) body(0);
    body(1);
    body(2);

    __syncthreads();
    cur ^= 1;
  }

  // epilogue: sum hi halves, write output directly
  float totA = skipA + __shfl_xor(skipA, 32);
  float totB = skipB + __shfl_xor(skipB, 32);
  if (hi == 0) {
    float mb = mix_b[0];
    int base = b * TT + t0 + X;
    outp[base] = totA + mb;
    outp[base + 512] = totB + mb;
  }
}

extern "C" void kernel_launch(void* const* d_in, const int* in_sizes, int n_in,
                              void* d_out, int out_size, void* d_ws, size_t ws_size,
                              hipStream_t stream) {
  const float* x     = (const float*)d_in[0];
  const float* in_w  = (const float*)d_in[1];
  const float* in_b  = (const float*)d_in[2];
  const float* hid_w = (const float*)d_in[3];
  const float* hid_b = (const float*)d_in[4];
  const float* res_w = (const float*)d_in[5];
  const float* res_b = (const float*)d_in[6];
  const float* mix_w = (const float*)d_in[7];
  const float* mix_b = (const float*)d_in[8];
  float* outp = (float*)d_out;

  ushort* WA = (ushort*)d_ws;          // 24576 ushorts
  ushort* RA = WA + 24576;             // 16384 ushorts

  wn_prep<<<160, 256, 0, stream>>>(hid_w, res_w, WA, RA);
  wn_fused<<<BB * (TT / TILE), 1024, 0, stream>>>(
      x, in_w, in_b, WA, RA, hid_b, res_b, mix_w, mix_b, outp);
}

// Round 13
// 81.928 us; speedup vs baseline: 6.1331x; 1.2326x over previous
//
#include <hip/hip_runtime.h>
#include <hip/hip_bf16.h>

#define LL 16
#define TT 32768
#define BB 8
#define TILE 1024                 // output t per block
#define BASEI 1152                // LDS row u = tau + BASEI (512-rounded halo)
#define NSLOT 2176                // rows per buffer
#define BUFB (NSLOT * 32)         // bytes per buffer (69632)

typedef unsigned int uint;
typedef unsigned short ushort;
typedef uint  u32x4 __attribute__((ext_vector_type(4)));
typedef float f32x4 __attribute__((ext_vector_type(4)));
typedef float f32x16 __attribute__((ext_vector_type(16)));
typedef short s16x8 __attribute__((ext_vector_type(8)));   // 8 bf16

#define S_T 2.885390081777927f     // 2*log2(e)  (tanh rows prescale)
#define S_S -1.4426950408889634f   // -log2(e)   (sigmoid rows prescale)

// stored-position p holds real channel perm[p] = (p&3) + 8*((p>>2)&1) + 4*(p>>3)
// => lane-group hi's C/D gate rows {4hi..4hi+3, 8+4hi..8+4hi+3} are stored
//    positions {8hi..8hi+7}: res B-frag needs NO cross-lane exchange, and the
//    res output write is one aligned b128 per lane.

__device__ __forceinline__ ushort f2bf(float f) {
  uint u = __float_as_uint(f);
  return (ushort)((u + 0x7FFFu + ((u >> 16) & 1u)) >> 16);   // RNE
}
__device__ __forceinline__ uint cvtpk(float lo, float hi) {
  __hip_bfloat162 h = __float22bfloat162_rn(float2{lo, hi});
  uint r;
  __builtin_memcpy(&r, &h, 4);
  return r;
}
__device__ __forceinline__ float fexp2(float x) {
#if __has_builtin(__builtin_amdgcn_exp2f)
  return __builtin_amdgcn_exp2f(x);
#else
  return exp2f(x);
#endif
}
__device__ __forceinline__ f32x16 mfma32(s16x8 a, s16x8 b, f32x16 c) {
  return __builtin_amdgcn_mfma_f32_32x32x16_bf16(a, b, c, 0, 0, 0);
}
// swizzle: addr = swzb(u) ^ o (o < 32); swzb(u+512) = swzb(u)+16384.
__device__ __forceinline__ int swzb(int u) {
  return (u << 5) ^ ((u & 28) << 2);
}
__device__ __forceinline__ int swz(int u, int o) { return swzb(u) ^ o; }

// ---------------- prep: pack weights into 32x32x16 fragment order -----------
// WA[l][kt][lane][j]: A row co=lane&31, K-slot s=(lane>>5)*8+j -> real channel
//   perm[s]; rows<16 prescaled S_T (tanh), rows>=16 S_S (sigmoid).
// RA[l][0]: rows 0-15 res weight R[row][perm[s]]; row 16 = mix_w[perm[s]];
//           rows 17-31 = 0.
// RA[l][1]: rows 0-15 identity delta(row, perm[s]); rows 16-31 = 0.
__global__ __launch_bounds__(256) void wn_prep(
    const float* __restrict__ hw, const float* __restrict__ rw,
    const float* __restrict__ mixw,
    ushort* __restrict__ WA, ushort* __restrict__ RA) {
  int tid = blockIdx.x * 256 + threadIdx.x;      // 40960 total
  if (tid < 24576) {
    int j = tid & 7, lane = (tid >> 3) & 63;
    int rem = tid >> 9;                          // l*3 + kt
    int kt = rem % 3, l = rem / 3;
    int row = lane & 31;
    int pci = (j & 3) + ((j & 4) << 1) + ((lane >> 5) << 2);   // perm[s]
    float scale = (row < 16) ? S_T : S_S;
    WA[tid] = f2bf(hw[((l * 32 + row) * 16 + pci) * 3 + kt] * scale);
  } else if (tid < 40960) {
    int r = tid - 24576;
    int j = r & 7, lane = (r >> 3) & 63;
    int rem = r >> 9;                            // l*2 + which
    int which = rem & 1, l = rem >> 1;
    int row = lane & 31;
    int pci = (j & 3) + ((j & 4) << 1) + ((lane >> 5) << 2);   // perm[s]
    float v = 0.f;
    if (which == 0) {
      if (row < 16)       v = rw[(l * 16 + row) * 16 + pci];
      else if (row == 16) v = mixw[l * 16 + pci];              // skip row
    } else {
      if (row < 16) v = (row == pci) ? 1.f : 0.f;              // identity
    }
    RA[r] = f2bf(v);
  }
}

// ---------------- fully fused WaveNet, 32x32 MFMA bodies ---------------------
__global__ __launch_bounds__(1024, 4) void wn_fused(
    const float* __restrict__ x, const float* __restrict__ in_w,
    const float* __restrict__ in_b,
    const ushort* __restrict__ WA, const ushort* __restrict__ RA,
    const float* __restrict__ hid_b, const float* __restrict__ res_b,
    const float* __restrict__ mix_w, const float* __restrict__ mix_b,
    float* __restrict__ outp) {
  __shared__ ushort sbuf[2][NSLOT * 16];   // 2 x 69632 B, swizzled [t][16ch] bf16

  int tid = threadIdx.x;
  int b = blockIdx.x & 7, tile = blockIdx.x >> 3;   // XCD<->batch affinity
  int t0 = tile * TILE;
  char* lds = (char*)sbuf;

  // ---- stage: input 1x1 conv into buf0 over tau in [-1152, 1024) ----
  for (int r = tid; r < NSLOT; r += 1024) {
    int t = t0 + r - BASEI;
    uint pk[8];
    if (t >= 0) {
      float xv = x[b * TT + t];
#pragma unroll
      for (int c = 0; c < 8; ++c) {
        float lo = fmaf(in_w[2 * c], xv, in_b[2 * c]);
        float hi = fmaf(in_w[2 * c + 1], xv, in_b[2 * c + 1]);
        pk[c] = cvtpk(lo, hi);
      }
    } else {
#pragma unroll
      for (int c = 0; c < 8; ++c) pk[c] = 0u;     // causal zero pad
    }
    // channel-permuted word order: positions (0-3,4-7|8-11,12-15) hold
    // channels (0-3,8-11|4-7,12-15)
    *(u32x4*)(lds + swz(r, 0))  = (u32x4){pk[0], pk[1], pk[4], pk[5]};
    *(u32x4*)(lds + swz(r, 16)) = (u32x4){pk[2], pk[3], pk[6], pk[7]};
  }
  __syncthreads();

  int lane = tid & 63, w = tid >> 6;
  int col32 = lane & 31, hi = lane >> 5;
  int oG  = hi << 4;          // B-frag load AND res-write byte offset
  int X = w * 32 + col32;     // this lane's output t (chunk A); B = X+512
  float skipA = 0.f, skipB = 0.f;
  int cur = 0;

  for (int i = 0; i < LL; ++i) {
    int D = 1 << (i & 7);
    int ost   = (i < 7) ? -1024 : ((i < 15) ? -512 : 0);   // 512-rounded spans
    int halos = (i < 7) ? 2 : ((i < 15) ? 1 : 0);
    bool last = (i == LL - 1);

    const s16x8* wa = (const s16x8*)(WA + (size_t)i * 1536);
    s16x8 wa0 = wa[lane];            // tap k=0 (prescaled)
    s16x8 wa1 = wa[64 + lane];       // tap k=1
    s16x8 wa2 = wa[128 + lane];      // tap k=2
    const s16x8* rp = (const s16x8*)(RA + (size_t)i * 1024);
    s16x8 ra1 = rp[lane];            // res weights + mix row 16
    s16x8 ra2 = rp[64 + lane];       // identity (residual add)

    // bias fragments, prescaled to exp2 domain
    f32x4 hb0 = *(const f32x4*)(hid_b + i * 32 + 4 * hi);
    f32x4 hb1 = *(const f32x4*)(hid_b + i * 32 + 8 + 4 * hi);
    f32x4 hb2 = *(const f32x4*)(hid_b + i * 32 + 16 + 4 * hi);
    f32x4 hb3 = *(const f32x4*)(hid_b + i * 32 + 24 + 4 * hi);
    f32x16 bini;
#pragma unroll
    for (int q = 0; q < 4; ++q) {
      bini[q] = hb0[q] * S_T; bini[4 + q] = hb1[q] * S_T;
      bini[8 + q] = hb2[q] * S_S; bini[12 + q] = hb3[q] * S_S;
    }
    f32x16 rini;
    if (!last) {
      f32x4 rb0 = *(const f32x4*)(res_b + i * 16 + 4 * hi);
      f32x4 rb1 = *(const f32x4*)(res_b + i * 16 + 8 + 4 * hi);
#pragma unroll
      for (int q = 0; q < 4; ++q) {
        rini[q] = rb0[q]; rini[4 + q] = rb1[q];
        rini[8 + q] = 0.f; rini[12 + q] = 0.f;
      }
    }
    f32x4 mwA = *(const f32x4*)(mix_w + i * 16 + 4 * hi);     // last layer only
    f32x4 mwB = *(const f32x4*)(mix_w + i * 16 + 8 + 4 * hi);

    int rb = cur * BUFB;
    int wdelta = cur ? -BUFB : BUFB;
    int u0 = ost + X + BASEI;
    int A2 = rb + swzb(u0);
    int A1 = rb + swzb(u0 - D);
    int A0 = rb + swzb(u0 - 2 * D);
    int tabs = t0 + ost + X;

    auto body = [&](int mode) {   // 0 = halo, 1 = output A, 2 = output B
      s16x8 q0 = *(const s16x8*)(lds + (A0 ^ oG));
      s16x8 q1 = *(const s16x8*)(lds + (A1 ^ oG));
      s16x8 q2 = *(const s16x8*)(lds + (A2 ^ oG));

      f32x16 acc = bini;
      acc = mfma32(wa0, q0, acc);
      acc = mfma32(wa1, q1, acc);
      acc = mfma32(wa2, q2, acc);

      // gated = (E-1)/((E+1)(F+1)), E=exp2(acc_t), F=exp2(acc_s); no clamps:
      // all LDS data is O(10), and inf/NaN would stay column-confined anyway.
      float gg[8];
#pragma unroll
      for (int r = 0; r < 8; ++r) {
        float E = fexp2(acc[r]);
        float F = fexp2(acc[r + 8]);
        gg[r] = (E - 1.f) * __builtin_amdgcn_rcpf((E + 1.f) * (F + 1.f));
      }

      if (!last) {
        // res B-frag = own gates (channel-permuted storage), no exchange
        uint O0 = cvtpk(gg[0], gg[1]);
        uint O1 = cvtpk(gg[2], gg[3]);
        uint O2 = cvtpk(gg[4], gg[5]);
        uint O3 = cvtpk(gg[6], gg[7]);
        u32x4 gw = {O0, O1, O2, O3};
        s16x8 gb = __builtin_bit_cast(s16x8, gw);

        f32x16 accr = rini;
        accr = mfma32(ra1, gb, accr);    // R @ gates + res_b ; row16 = mix dot
        accr = mfma32(ra2, q2, accr);    // + identity @ center taps (residual)

        if (mode == 1) skipA += accr[8];        // row16 (hi=1 adds 0)
        else if (mode == 2) skipB += accr[8];

        uint o0 = cvtpk(accr[0], accr[1]);
        uint o1 = cvtpk(accr[2], accr[3]);
        uint o2 = cvtpk(accr[4], accr[5]);
        uint o3 = cvtpk(accr[6], accr[7]);
        if (mode == 0 && tabs < 0) { o0 = 0u; o1 = 0u; o2 = 0u; o3 = 0u; }
        *(u32x4*)(lds + ((A2 + wdelta) ^ oG)) = (u32x4){o0, o1, o2, o3};
      } else {
        float s = gg[0] * mwA[0];
        s = fmaf(gg[1], mwA[1], s);
        s = fmaf(gg[2], mwA[2], s);
        s = fmaf(gg[3], mwA[3], s);
        s = fmaf(gg[4], mwB[0], s);
        s = fmaf(gg[5], mwB[1], s);
        s = fmaf(gg[6], mwB[2], s);
        s = fmaf(gg[7], mwB[3], s);
        if (mode == 1) skipA += s; else skipB += s;
      }

      A0 += 16384; A1 += 16384; A2 += 16384;
      tabs += 512;
    };

    for (int h = 0; h < halos; ++h) body(0);
    body(1);
    body(2);

    __syncthreads();
    cur ^= 1;
  }

  // epilogue: sum hi halves, write output directly
  float totA = skipA + __shfl_xor(skipA, 32);
  float totB = skipB + __shfl_xor(skipB, 32);
  if (hi == 0) {
    float mb = mix_b[0];
    int base = b * TT + t0 + X;
    outp[base] = totA + mb;
    outp[base + 512] = totB + mb;
  }
}

extern "C" void kernel_launch(void* const* d_in, const int* in_sizes, int n_in,
                              void* d_out, int out_size, void* d_ws, size_t ws_size,
                              hipStream_t stream) {
  const float* x     = (const float*)d_in[0];
  const float* in_w  = (const float*)d_in[1];
  const float* in_b  = (const float*)d_in[2];
  const float* hid_w = (const float*)d_in[3];
  const float* hid_b = (const float*)d_in[4];
  const float* res_w = (const float*)d_in[5];
  const float* res_b = (const float*)d_in[6];
  const float* mix_w = (const float*)d_in[7];
  const float* mix_b = (const float*)d_in[8];
  float* outp = (float*)d_out;

  ushort* WA = (ushort*)d_ws;          // 24576 ushorts
  ushort* RA = WA + 24576;             // 16384 ushorts

  wn_prep<<<160, 256, 0, stream>>>(hid_w, res_w, mix_w, WA, RA);
  wn_fused<<<BB * (TT / TILE), 1024, 0, stream>>>(
      x, in_w, in_b, WA, RA, hid_b, res_b, mix_w, mix_b, outp);
}

// Round 14
// 76.017 us; speedup vs baseline: 6.6100x; 1.0778x over previous
//
#include <hip/hip_runtime.h>
#include <hip/hip_bf16.h>

#define LL 16
#define TT 32768
#define BB 8
#define TILE 1024                 // output t per block
#define BASEI 1152                // LDS row u = tau + BASEI (512-rounded halo)
#define NSLOT 2176                // rows per buffer
#define BUFB (NSLOT * 32)         // bytes per buffer (69632)

typedef unsigned int uint;
typedef unsigned short ushort;
typedef uint  u32x4 __attribute__((ext_vector_type(4)));
typedef float f32x4 __attribute__((ext_vector_type(4)));
typedef float f32p2 __attribute__((ext_vector_type(2)));   // packed f32 pair
typedef float f32x16 __attribute__((ext_vector_type(16)));
typedef short s16x8 __attribute__((ext_vector_type(8)));   // 8 bf16

#define S_T 2.885390081777927f     // 2*log2(e)  (tanh rows prescale)
#define S_S -1.4426950408889634f   // -log2(e)   (sigmoid rows prescale)

template <int N> struct IC { static constexpr int value = N; };

__device__ __forceinline__ ushort f2bf(float f) {
  uint u = __float_as_uint(f);
  return (ushort)((u + 0x7FFFu + ((u >> 16) & 1u)) >> 16);   // RNE
}
__device__ __forceinline__ uint cvtpk(float lo, float hi) {
  __hip_bfloat162 h = __float22bfloat162_rn(float2{lo, hi});
  uint r;
  __builtin_memcpy(&r, &h, 4);
  return r;
}
__device__ __forceinline__ float fexp2(float x) {
#if __has_builtin(__builtin_amdgcn_exp2f)
  return __builtin_amdgcn_exp2f(x);
#else
  return exp2f(x);
#endif
}
__device__ __forceinline__ f32x16 mfma32(s16x8 a, s16x8 b, f32x16 c) {
  return __builtin_amdgcn_mfma_f32_32x32x16_bf16(a, b, c, 0, 0, 0);
}
// swizzle: addr = swzb(u) ^ o (o < 32); swzb(u+512) = swzb(u)+16384.
__device__ __forceinline__ int swzb(int u) {
  return (u << 5) ^ ((u & 28) << 2);
}
__device__ __forceinline__ int swz(int u, int o) { return swzb(u) ^ o; }

// ---------------- prep: pack weights into 32x32x16 fragment order -----------
// stored-position p holds real channel perm[p] = (p&3)+8*((p>>2)&1)+4*(p>>3)
// WA[l][kt][lane][j]: A row co=lane&31, K-slot -> perm'd channel; rows<16
//   prescaled S_T (tanh), rows>=16 S_S (sigmoid).
// RA[l][0]: rows 0-15 res weight; row 16 = mix_w (skip dot rides the MFMA).
// RA[l][1]: rows 0-15 identity (residual add); rest 0.
__global__ __launch_bounds__(256) void wn_prep(
    const float* __restrict__ hw, const float* __restrict__ rw,
    const float* __restrict__ mixw,
    ushort* __restrict__ WA, ushort* __restrict__ RA) {
  int tid = blockIdx.x * 256 + threadIdx.x;      // 40960 total
  if (tid < 24576) {
    int j = tid & 7, lane = (tid >> 3) & 63;
    int rem = tid >> 9;                          // l*3 + kt
    int kt = rem % 3, l = rem / 3;
    int row = lane & 31;
    int pci = (j & 3) + ((j & 4) << 1) + ((lane >> 5) << 2);   // perm[s]
    float scale = (row < 16) ? S_T : S_S;
    WA[tid] = f2bf(hw[((l * 32 + row) * 16 + pci) * 3 + kt] * scale);
  } else if (tid < 40960) {
    int r = tid - 24576;
    int j = r & 7, lane = (r >> 3) & 63;
    int rem = r >> 9;                            // l*2 + which
    int which = rem & 1, l = rem >> 1;
    int row = lane & 31;
    int pci = (j & 3) + ((j & 4) << 1) + ((lane >> 5) << 2);   // perm[s]
    float v = 0.f;
    if (which == 0) {
      if (row < 16)       v = rw[(l * 16 + row) * 16 + pci];
      else if (row == 16) v = mixw[l * 16 + pci];              // skip row
    } else {
      if (row < 16) v = (row == pci) ? 1.f : 0.f;              // identity
    }
    RA[r] = f2bf(v);
  }
}

// ---------------- fully fused WaveNet, 32x32 MFMA bodies ---------------------
__global__ __launch_bounds__(1024, 4) void wn_fused(
    const float* __restrict__ x, const float* __restrict__ in_w,
    const float* __restrict__ in_b,
    const ushort* __restrict__ WA, const ushort* __restrict__ RA,
    const float* __restrict__ hid_b, const float* __restrict__ res_b,
    const float* __restrict__ mix_w, const float* __restrict__ mix_b,
    float* __restrict__ outp) {
  __shared__ ushort sbuf[2][NSLOT * 16];   // 2 x 69632 B, swizzled [t][16ch] bf16

  int tid = threadIdx.x;
  int b = blockIdx.x & 7, tile = blockIdx.x >> 3;   // XCD<->batch affinity
  int t0 = tile * TILE;
  char* lds = (char*)sbuf;

  // ---- stage: input 1x1 conv into buf0 over tau in [-1152, 1024) ----
  for (int r = tid; r < NSLOT; r += 1024) {
    int t = t0 + r - BASEI;
    uint pk[8];
    if (t >= 0) {
      float xv = x[b * TT + t];
#pragma unroll
      for (int c = 0; c < 8; ++c) {
        float lo = fmaf(in_w[2 * c], xv, in_b[2 * c]);
        float hi = fmaf(in_w[2 * c + 1], xv, in_b[2 * c + 1]);
        pk[c] = cvtpk(lo, hi);
      }
    } else {
#pragma unroll
      for (int c = 0; c < 8; ++c) pk[c] = 0u;     // causal zero pad
    }
    // channel-permuted word order
    *(u32x4*)(lds + swz(r, 0))  = (u32x4){pk[0], pk[1], pk[4], pk[5]};
    *(u32x4*)(lds + swz(r, 16)) = (u32x4){pk[2], pk[3], pk[6], pk[7]};
  }
  __syncthreads();

  int lane = tid & 63, w = tid >> 6;
  int col32 = lane & 31, hi = lane >> 5;
  int oG  = hi << 4;          // B-frag load AND res-write byte offset
  int X = w * 32 + col32;     // this lane's output t (chunk A); B = X+512
  float skipA = 0.f, skipB = 0.f;
  int cur = 0;

  for (int i = 0; i < LL; ++i) {
    int D = 1 << (i & 7);
    int ost = (i < 7) ? -1024 : ((i < 15) ? -512 : 0);   // 512-rounded spans
    bool last = (i == LL - 1);

    const s16x8* wa = (const s16x8*)(WA + (size_t)i * 1536);
    s16x8 wa0 = wa[lane];            // tap k=0 (prescaled)
    s16x8 wa1 = wa[64 + lane];       // tap k=1
    s16x8 wa2 = wa[128 + lane];      // tap k=2
    const s16x8* rp = (const s16x8*)(RA + (size_t)i * 1024);
    s16x8 ra1 = rp[lane];            // res weights + mix row 16
    s16x8 ra2 = rp[64 + lane];       // identity (residual add)

    // bias fragments, prescaled to exp2 domain
    f32x4 hb0 = *(const f32x4*)(hid_b + i * 32 + 4 * hi);
    f32x4 hb1 = *(const f32x4*)(hid_b + i * 32 + 8 + 4 * hi);
    f32x4 hb2 = *(const f32x4*)(hid_b + i * 32 + 16 + 4 * hi);
    f32x4 hb3 = *(const f32x4*)(hid_b + i * 32 + 24 + 4 * hi);
    f32x16 bini;
#pragma unroll
    for (int q = 0; q < 4; ++q) {
      bini[q] = hb0[q] * S_T; bini[4 + q] = hb1[q] * S_T;
      bini[8 + q] = hb2[q] * S_S; bini[12 + q] = hb3[q] * S_S;
    }
    f32x16 rini;
    if (!last) {
      f32x4 rb0 = *(const f32x4*)(res_b + i * 16 + 4 * hi);
      f32x4 rb1 = *(const f32x4*)(res_b + i * 16 + 8 + 4 * hi);
#pragma unroll
      for (int q = 0; q < 4; ++q) {
        rini[q] = rb0[q]; rini[4 + q] = rb1[q];
        rini[8 + q] = 0.f; rini[12 + q] = 0.f;
      }
    }
    f32x4 mwA = *(const f32x4*)(mix_w + i * 16 + 4 * hi);     // last layer only
    f32x4 mwB = *(const f32x4*)(mix_w + i * 16 + 8 + 4 * hi);

    int rb = cur * BUFB;
    int wdelta = cur ? -BUFB : BUFB;
    int u0 = ost + X + BASEI;
    int A2 = rb + swzb(u0);
    int A1 = rb + swzb(u0 - D);
    int A0 = rb + swzb(u0 - 2 * D);
    int tb0 = t0 + ost + X;

    // NB bodies: NB-2 halo, then output A, output B. Depth-1 load pipeline.
    auto run = [&](auto nbc) {
      constexpr int NB = decltype(nbc)::value;
      s16x8 c0 = *(const s16x8*)(lds + (A0 ^ oG));
      s16x8 c1 = *(const s16x8*)(lds + (A1 ^ oG));
      s16x8 c2 = *(const s16x8*)(lds + (A2 ^ oG));
#pragma unroll
      for (int bb = 0; bb < NB; ++bb) {
        const int mode = (bb < NB - 2) ? 0 : ((bb == NB - 2) ? 1 : 2);
        s16x8 n0, n1, n2;
        if (bb + 1 < NB) {        // prefetch next body's taps
          n0 = *(const s16x8*)(lds + ((A0 + (bb + 1) * 16384) ^ oG));
          n1 = *(const s16x8*)(lds + ((A1 + (bb + 1) * 16384) ^ oG));
          n2 = *(const s16x8*)(lds + ((A2 + (bb + 1) * 16384) ^ oG));
        }

        f32x16 acc = mfma32(wa0, c0, bini);
        acc = mfma32(wa1, c1, acc);
        acc = mfma32(wa2, c2, acc);

        // gated = (E-1)/((E+1)(F+1)); packed-f32 arithmetic, exp2 domain
        f32p2 G[4];
#pragma unroll
        for (int p = 0; p < 4; ++p) {
          f32p2 E = {fexp2(acc[2 * p]), fexp2(acc[2 * p + 1])};
          f32p2 F = {fexp2(acc[2 * p + 8]), fexp2(acc[2 * p + 9])};
          f32p2 num = E - 1.f;
          f32p2 den = (E + 1.f) * (F + 1.f);
          f32p2 R = {__builtin_amdgcn_rcpf(den.x), __builtin_amdgcn_rcpf(den.y)};
          G[p] = num * R;
        }

        if (!last) {
          uint O0 = cvtpk(G[0].x, G[0].y);
          uint O1 = cvtpk(G[1].x, G[1].y);
          uint O2 = cvtpk(G[2].x, G[2].y);
          uint O3 = cvtpk(G[3].x, G[3].y);
          u32x4 gw = {O0, O1, O2, O3};
          s16x8 gb = __builtin_bit_cast(s16x8, gw);

          f32x16 accr = mfma32(ra1, gb, rini);   // R@gates + res_b; row16=mix
          accr = mfma32(ra2, c2, accr);          // + identity @ center taps

          if (mode == 1) skipA += accr[8];       // row16 (hi=1 adds 0)
          else if (mode == 2) skipB += accr[8];

          uint o0 = cvtpk(accr[0], accr[1]);
          uint o1 = cvtpk(accr[2], accr[3]);
          uint o2 = cvtpk(accr[4], accr[5]);
          uint o3 = cvtpk(accr[6], accr[7]);
          if (mode == 0 && (tb0 + 512 * bb) < 0) { o0 = o1 = o2 = o3 = 0u; }
          *(u32x4*)(lds + ((A2 + bb * 16384 + wdelta) ^ oG)) =
              (u32x4){o0, o1, o2, o3};
        } else {
          float s = G[0].x * mwA[0];
          s = fmaf(G[0].y, mwA[1], s);
          s = fmaf(G[1].x, mwA[2], s);
          s = fmaf(G[1].y, mwA[3], s);
          s = fmaf(G[2].x, mwB[0], s);
          s = fmaf(G[2].y, mwB[1], s);
          s = fmaf(G[3].x, mwB[2], s);
          s = fmaf(G[3].y, mwB[3], s);
          if (mode == 1) skipA += s; else skipB += s;
        }

        c0 = n0; c1 = n1; c2 = n2;   // renamed away by full unroll
      }
    };

    if (i < 7)       run(IC<4>{});
    else if (i < 15) run(IC<3>{});
    else             run(IC<2>{});

    __syncthreads();
    cur ^= 1;
  }

  // epilogue: sum hi halves, write output directly
  float totA = skipA + __shfl_xor(skipA, 32);
  float totB = skipB + __shfl_xor(skipB, 32);
  if (hi == 0) {
    float mb = mix_b[0];
    int base = b * TT + t0 + X;
    outp[base] = totA + mb;
    outp[base + 512] = totB + mb;
  }
}

extern "C" void kernel_launch(void* const* d_in, const int* in_sizes, int n_in,
                              void* d_out, int out_size, void* d_ws, size_t ws_size,
                              hipStream_t stream) {
  const float* x     = (const float*)d_in[0];
  const float* in_w  = (const float*)d_in[1];
  const float* in_b  = (const float*)d_in[2];
  const float* hid_w = (const float*)d_in[3];
  const float* hid_b = (const float*)d_in[4];
  const float* res_w = (const float*)d_in[5];
  const float* res_b = (const float*)d_in[6];
  const float* mix_w = (const float*)d_in[7];
  const float* mix_b = (const float*)d_in[8];
  float* outp = (float*)d_out;

  ushort* WA = (ushort*)d_ws;          // 24576 ushorts
  ushort* RA = WA + 24576;             // 16384 ushorts

  wn_prep<<<160, 256, 0, stream>>>(hid_w, res_w, mix_w, WA, RA);
  wn_fused<<<BB * (TT / TILE), 1024, 0, stream>>>(
      x, in_w, in_b, WA, RA, hid_b, res_b, mix_w, mix_b, outp);
}